// Round 4
// baseline (517.350 us; speedup 1.0000x reference)
//
#include <hip/hip_runtime.h>
#include <hip/hip_bf16.h>

// RNN-T joint network. B=4 T=256 U=64 D=512 J=512 V=1024.
//   Pe = enc @ W_enc^T + b_enc   (1024 x 512)  fp32 in ws
//   Pd = dec @ W_dec^T           (256  x 512)  fp32 in ws
//   out[m,:] = tanh(Pe[m>>6] + Pd[(m>>14)*64 + (m&63)]) @ W_out^T + b_out
//
// gemm_joint (round-4): BARRIER-FREE main loop.
//   Round-3 post-mortem: 16x16x32 @ wave-tile 32x32 was LDS-read-bound
//   (64KB LDS per CU-iter for 1.05 MFLOP) and paid a vmcnt(0)+barrier
//   drain every 4 MFMAs. Fixes:
//   - 32x32x16 MFMA (2x FLOP per LDS byte), wave-tile 32(M)x64(N),
//     acc = 2 x f32x16.
//   - B operand loaded L2->registers directly (W_out is 1MB, L2-resident;
//     512MB total re-read = ~15us of L2 BW). NO sB, NO barriers in the
//     k-loop -- the only __syncthreads is after the tanh phase. Prefetch
//     depth 2, compiler-counted vmcnt (no barrier ever forces a drain).
//   - sH 64KB only -> 2 workgroups/CU at 512 threads.
// Floors: MFMA 27.5us, HBM-write 43us -> expect write-bound ~50-70us.
// sH swizzle: chunk c stored/read at c ^ (r&7) ^ (((r>>3)&1)<<3)
//   (16-slot involution; uniform bank spread for 32-row b128 reads AND
//    64-row b128 writes -- derivation: banks repeat per 128B, 16B chunks,
//    8 slots/row-line; spread rows over 16 slots -> BW-floor, no conflict).

typedef __attribute__((ext_vector_type(8))) short short8;     // 8 bf16
typedef __attribute__((ext_vector_type(4))) float f32x4;
typedef __attribute__((ext_vector_type(16))) float f32x16;

#define SZ0 524288
#define SZ1 131072
#define SZ2 262144
#define SZ3 512
#define SZ4 262144
#define SZ5 524288
#define SZ6 1024
#define CU0 0
#define CU1 524288
#define CU2 655360
#define CU3 917504
#define CU4 918016
#define CU5 1180160
#define CU6 1704448
#define CTOT 1705472

// ---------------------------------------------------------------------------
// Runtime dtype detection (unchanged).
// ---------------------------------------------------------------------------
__global__ void detect_kernel(const void* p0, const void* p1, const void* p2,
                              const void* p3, const void* p4, const void* p5,
                              const void* p6, int* flags) {
  const void* ps[7] = {p0, p1, p2, p3, p4, p5, p6};
  const int sz[7] = {SZ0, SZ1, SZ2, SZ3, SZ4, SZ5, SZ6};
  const int w = threadIdx.x >> 6;
  const int l = threadIdx.x & 63;
  if (w >= 7) return;
  const unsigned short* u = (const unsigned short*)ps[w];
  const int lim = sz[w] < 1024 ? sz[w] : 1024;
  int bad = 0;
  for (int j = l; j < lim; j += 64) {
    const unsigned e = (u[j] >> 7) & 0xFFu;
    if (e >= 0x8Eu) bad = 1;
  }
  const unsigned long long b = __ballot(bad);
  if (l == 0) flags[w] = (b != 0ULL) ? 1 : 0;
}

__global__ __launch_bounds__(256) void convert_kernel(
    const void* p0, const void* p1, const void* p2, const void* p3,
    const void* p4, const void* p5, const void* p6,
    const int* __restrict__ flags, __hip_bfloat16* __restrict__ dst) {
  const int gid = blockIdx.x * 256 + threadIdx.x;
  if (gid >= CTOT) return;
  int t, local;
  const void* p;
  if (gid < CU1)      { t = 0; local = gid - CU0; p = p0; }
  else if (gid < CU2) { t = 1; local = gid - CU1; p = p1; }
  else if (gid < CU3) { t = 2; local = gid - CU2; p = p2; }
  else if (gid < CU4) { t = 3; local = gid - CU3; p = p3; }
  else if (gid < CU5) { t = 4; local = gid - CU4; p = p4; }
  else if (gid < CU6) { t = 5; local = gid - CU5; p = p5; }
  else                { t = 6; local = gid - CU6; p = p6; }
  __hip_bfloat16 v;
  if (flags[t])
    v = __float2bfloat16(((const float*)p)[local]);
  else
    v = ((const __hip_bfloat16*)p)[local];
  dst[gid] = v;
}

// ---------------------------------------------------------------------------
// m97-structure GEMM body for the two small projections (unchanged).
// ---------------------------------------------------------------------------
__device__ __forceinline__ void gemm_bt_body(
    const __hip_bfloat16* __restrict__ A, const __hip_bfloat16* __restrict__ Bw,
    const __hip_bfloat16* __restrict__ bias, float* __restrict__ C,
    int M, int N, int K, int bid,
    __hip_bfloat16* sA, __hip_bfloat16* sB) {
  const int tid = threadIdx.x;
  const int w = tid >> 6;
  const int l = tid & 63;
  const int ntiles = N >> 7;
  const int mt = bid / ntiles;
  const int nt = bid % ntiles;
  const int m0 = mt << 7;
  const int n0 = nt << 7;
  const int wm = (w >> 1) << 6;
  const int wn = (w & 1) << 6;
  const int r16 = l & 15;
  const int q = l >> 4;

  f32x4 acc[4][4] = {};

  const int srow_in = l >> 3;
  const int scol = (l & 7) << 3;

  for (int k0 = 0; k0 < K; k0 += 64) {
#pragma unroll
    for (int i = 0; i < 4; ++i) {
      const int c = (w << 2) + i;
      const int row = (c << 3) + srow_in;
      const __hip_bfloat16* gA = A + (size_t)(m0 + row) * K + k0 + scol;
      const __hip_bfloat16* gB = Bw + (size_t)(n0 + row) * K + k0 + scol;
      __builtin_amdgcn_global_load_lds(
          (const __attribute__((address_space(1))) void*)gA,
          (__attribute__((address_space(3))) void*)(sA + (c << 9) + (l << 3)),
          16, 0, 0);
      __builtin_amdgcn_global_load_lds(
          (const __attribute__((address_space(1))) void*)gB,
          (__attribute__((address_space(3))) void*)(sB + (c << 9) + (l << 3)),
          16, 0, 0);
    }
    __syncthreads();

#pragma unroll
    for (int kk = 0; kk < 2; ++kk) {
      const int kc = (kk << 5) + (q << 3);
      short8 af[4], bf[4];
#pragma unroll
      for (int mi = 0; mi < 4; ++mi)
        af[mi] = *(const short8*)(sA + (wm + (mi << 4) + r16) * 64 + kc);
#pragma unroll
      for (int ni = 0; ni < 4; ++ni)
        bf[ni] = *(const short8*)(sB + (wn + (ni << 4) + r16) * 64 + kc);
#pragma unroll
      for (int mi = 0; mi < 4; ++mi)
#pragma unroll
        for (int ni = 0; ni < 4; ++ni)
          acc[mi][ni] = __builtin_amdgcn_mfma_f32_16x16x32_bf16(
              af[mi], bf[ni], acc[mi][ni], 0, 0, 0);
    }
    __syncthreads();
  }

#pragma unroll
  for (int ni = 0; ni < 4; ++ni) {
    const int col = n0 + wn + (ni << 4) + r16;
    const float bc = bias ? __bfloat162float(bias[col]) : 0.0f;
#pragma unroll
    for (int mi = 0; mi < 4; ++mi) {
      const int rowb = m0 + wm + (mi << 4) + (q << 2);
#pragma unroll
      for (int i = 0; i < 4; ++i)
        C[(size_t)(rowb + i) * N + col] = acc[mi][ni][i] + bc;
    }
  }
}

__global__ __launch_bounds__(256) void proj_kernel(
    const __hip_bfloat16* __restrict__ enc, const __hip_bfloat16* __restrict__ Wenc,
    const __hip_bfloat16* __restrict__ benc,
    const __hip_bfloat16* __restrict__ dec, const __hip_bfloat16* __restrict__ Wdec,
    float* __restrict__ Pe, float* __restrict__ Pd) {
  __shared__ __align__(16) __hip_bfloat16 sA[128 * 64];
  __shared__ __align__(16) __hip_bfloat16 sB[128 * 64];
  if (blockIdx.x < 32)
    gemm_bt_body(enc, Wenc, benc, Pe, 1024, 512, 512, blockIdx.x, sA, sB);
  else
    gemm_bt_body(dec, Wdec, nullptr, Pd, 256, 512, 512, blockIdx.x - 32, sA, sB);
}

// ---------------------------------------------------------------------------
// Main fused GEMM. grid = 1024 blocks (BM=64), 512 threads (8 waves),
// 2 WGs/CU (64KB LDS, ~100 VGPR). Waves: wm=(w&1)*32, wn=(w>>1)*64.
// 4 nt-chunks (BN=256) x 32 k-steps (K=16 each, 32x32x16 MFMA).
// Per k-step/wave: 1 ds_read_b128 (A), 2 global dwordx4 (B, depth-2
// prefetch), 2 MFMA. No barriers after the tanh phase.
// ---------------------------------------------------------------------------
__global__ __launch_bounds__(512, 4) void gemm_joint(
    const float* __restrict__ Pe, const float* __restrict__ Pd,
    const __hip_bfloat16* __restrict__ Bw,
    const __hip_bfloat16* __restrict__ bias, float* __restrict__ out) {
  __shared__ __align__(16) __hip_bfloat16 sH[64 * 512];    // 64 KB

  const int t = threadIdx.x;
  const int w = t >> 6;
  const int l = t & 63;
  const int l31 = l & 31;
  const int q2 = l >> 5;
  const int m0 = blockIdx.x << 6;

  // Phase 1: sH = tanh(Pe[e] + Pd[d]); e = blockIdx (one Pe row for the
  // whole block), d = (blockIdx>>8)*64 + r. Swizzled 16-slot store.
  {
    const int r = t & 63;           // H row
    const int seg = t >> 6;         // 0..7, 64-col segment
    const int e = blockIdx.x;
    const int d = ((blockIdx.x >> 8) << 6) | r;
    const float* pe = Pe + (size_t)e * 512 + (seg << 6);
    const float* pd = Pd + (size_t)d * 512 + (seg << 6);
    const int swr = (r & 7) ^ (((r >> 3) & 1) << 3);
#pragma unroll
    for (int i = 0; i < 8; ++i) {
      const int cc = (seg << 3) + i;            // chunk index 0..63
      const f32x4 a0 = *(const f32x4*)(pe + (i << 3));
      const f32x4 a1 = *(const f32x4*)(pe + (i << 3) + 4);
      const f32x4 b0 = *(const f32x4*)(pd + (i << 3));
      const f32x4 b1 = *(const f32x4*)(pd + (i << 3) + 4);
      short8 hv;
#pragma unroll
      for (int jj = 0; jj < 4; ++jj) {
        float s = a0[jj] + b0[jj];
        float tv = 1.0f - 2.0f / (__expf(2.0f * s) + 1.0f);
        __hip_bfloat16 hb = __float2bfloat16(tv);
        hv[jj] = *(const short*)&hb;
        s = a1[jj] + b1[jj];
        tv = 1.0f - 2.0f / (__expf(2.0f * s) + 1.0f);
        hb = __float2bfloat16(tv);
        hv[4 + jj] = *(const short*)&hb;
      }
      *(short8*)(sH + (r << 9) + ((cc ^ swr) << 3)) = hv;
    }
  }
  __syncthreads();  // the ONLY barrier: sH is read-only from here on

  const int wm = (w & 1) << 5;    // 0 or 32 (M)
  const int wn = (w >> 1) << 6;   // 0,64,128,192 (N within nt-chunk)
  const int aoff = (wm + l31) << 9;                       // sH row base
  const int swz = (l & 7) ^ (((l >> 3) & 1) << 3);        // read swizzle

  for (int nt = 0; nt < 4; ++nt) {
    const int n0 = nt << 8;
    // B fragment pointers: lane reads W_out[n0+wn+ni*32+l31][k .. k+8],
    // k = ks*16 + q2*8 (32x32x16 A/B layout: row=l&31, k=(l>>5)*8+j).
    const __hip_bfloat16* bp0 = Bw + (size_t)(n0 + wn + l31) * 512 + (q2 << 3);
    const __hip_bfloat16* bp1 = bp0 + (32 * 512);
    short8 c0 = *(const short8*)(bp0);         // ks=0
    short8 c1 = *(const short8*)(bp1);
    short8 d0 = *(const short8*)(bp0 + 16);    // ks=1
    short8 d1 = *(const short8*)(bp1 + 16);
    f32x16 acc0 = {};
    f32x16 acc1 = {};
#pragma unroll 4
    for (int kp = 0; kp < 16; ++kp) {          // 2 k-steps per kp
      const int ks0 = kp << 1;
      const int ks1 = ks0 + 1;
      // depth-2 prefetch (wrap &31: tail loads read valid data, unused)
      const short8 p0a = *(const short8*)(bp0 + (((ks0 + 2) & 31) << 4));
      const short8 p0b = *(const short8*)(bp1 + (((ks0 + 2) & 31) << 4));
      const short8 p1a = *(const short8*)(bp0 + (((ks1 + 2) & 31) << 4));
      const short8 p1b = *(const short8*)(bp1 + (((ks1 + 2) & 31) << 4));
      const short8 afA =
          *(const short8*)(sH + aoff + ((((ks0 << 1) + q2) ^ swz) << 3));
      acc0 = __builtin_amdgcn_mfma_f32_32x32x16_bf16(afA, c0, acc0, 0, 0, 0);
      acc1 = __builtin_amdgcn_mfma_f32_32x32x16_bf16(afA, c1, acc1, 0, 0, 0);
      const short8 afB =
          *(const short8*)(sH + aoff + ((((ks1 << 1) + q2) ^ swz) << 3));
      acc0 = __builtin_amdgcn_mfma_f32_32x32x16_bf16(afB, d0, acc0, 0, 0, 0);
      acc1 = __builtin_amdgcn_mfma_f32_32x32x16_bf16(afB, d1, acc1, 0, 0, 0);
      c0 = p0a; c1 = p0b; d0 = p1a; d1 = p1b;
    }

    // C/D layout (32x32, m74/m101): col = l&31, row = (r&3)+8*(r>>2)+4*q2.
    const int colb = n0 + wn + l31;
    const float bc0 = __bfloat162float(bias[colb]);
    const float bc1 = __bfloat162float(bias[colb + 32]);
#pragma unroll
    for (int r = 0; r < 16; ++r) {
      const int row = m0 + wm + (r & 3) + ((r >> 2) << 3) + (q2 << 2);
      out[(size_t)row * 1024 + colb] = acc0[r] + bc0;
      out[(size_t)row * 1024 + colb + 32] = acc1[r] + bc1;
    }
  }
}

// ---------------------------------------------------------------------------
extern "C" void kernel_launch(void* const* d_in, const int* in_sizes, int n_in,
                              void* d_out, int out_size, void* d_ws,
                              size_t ws_size, hipStream_t stream) {
  // ws layout: 0 flags (7 ints) | 256 bf16 copies (3.41MB) | 4MB Pe | 6MB Pd
  char* ws = (char*)d_ws;
  int* flags = (int*)ws;
  __hip_bfloat16* cp = (__hip_bfloat16*)(ws + 256);
  float* Pe = (float*)(ws + (4ull << 20));
  float* Pd = (float*)(ws + (6ull << 20));

  detect_kernel<<<dim3(1), dim3(512), 0, stream>>>(
      d_in[0], d_in[1], d_in[2], d_in[3], d_in[4], d_in[5], d_in[6], flags);
  convert_kernel<<<dim3((CTOT + 255) / 256), dim3(256), 0, stream>>>(
      d_in[0], d_in[1], d_in[2], d_in[3], d_in[4], d_in[5], d_in[6], flags, cp);

  const __hip_bfloat16* enc_c = cp + CU0;
  const __hip_bfloat16* dec_c = cp + CU1;
  const __hip_bfloat16* Wenc_c = cp + CU2;
  const __hip_bfloat16* benc_c = cp + CU3;
  const __hip_bfloat16* Wdec_c = cp + CU4;
  const __hip_bfloat16* Wout_c = cp + CU5;
  const __hip_bfloat16* bout_c = cp + CU6;

  proj_kernel<<<dim3(40), dim3(256), 0, stream>>>(enc_c, Wenc_c, benc_c,
                                                  dec_c, Wdec_c, Pe, Pd);
  gemm_joint<<<dim3(1024), dim3(512), 0, stream>>>(
      Pe, Pd, Wout_c, bout_c, (float*)d_out);
}

// Round 5
// 482.441 us; speedup vs baseline: 1.0724x; 1.0724x over previous
//
#include <hip/hip_runtime.h>
#include <hip/hip_bf16.h>

// RNN-T joint network. B=4 T=256 U=64 D=512 J=512 V=1024.
//   Pe = enc @ W_enc^T + b_enc   (1024 x 512)  fp32 in ws
//   Pd = dec @ W_dec^T           (256  x 512)  fp32 in ws
//   out[m,:] = tanh(Pe[m>>6] + Pd[(m>>14)*64 + (m&63)]) @ W_out^T + b_out
//
// gemm_joint (round-5): BM=128, full-K H in LDS (128KB, tanh ONCE),
// BN=512 (2 nt-passes), BK=16, sB K-major dbuf 2x16KB -> 160KB LDS exact.
// 1024 threads = 16 waves (4/SIMD), wave-tile 64x64, 32x32x16 MFMA
// (layouts harness-verified in round 4). Per k-step/CU: MFMA 517cy,
// LDS 80KB ~625-940cy (mildly LDS-bound ~ at the 43us HBM-write wall).
// Round-3 lesson: stage->drain gap must be >= L2 latency (here ~550cy ok).
// Round-4 lesson: B must flow through LDS (128B/cy), not the ~64B/cy
// global path; B-direct left both pipes idle (MfmaUtil 9.9%).
// Swizzles:
//   sH: chunk c of row r at slot c ^ (r&63)  (involution, store=read side;
//       32-row b128 reads AND 64-row writes both at bank-BW floor)
//   sB: K-major [c][n] layout -- natively conflict-free (read bank-group
//       = n&7 -> 8 groups x 4 lanes = b128 floor), gload_lds dest linear.

typedef __attribute__((ext_vector_type(8))) short short8;     // 8 bf16
typedef __attribute__((ext_vector_type(4))) float f32x4;
typedef __attribute__((ext_vector_type(16))) float f32x16;

#define SZ0 524288
#define SZ1 131072
#define SZ2 262144
#define SZ3 512
#define SZ4 262144
#define SZ5 524288
#define SZ6 1024
#define CU0 0
#define CU1 524288
#define CU2 655360
#define CU3 917504
#define CU4 918016
#define CU5 1180160
#define CU6 1704448
#define CTOT 1705472

// ---------------------------------------------------------------------------
// Runtime dtype detection (unchanged).
// ---------------------------------------------------------------------------
__global__ void detect_kernel(const void* p0, const void* p1, const void* p2,
                              const void* p3, const void* p4, const void* p5,
                              const void* p6, int* flags) {
  const void* ps[7] = {p0, p1, p2, p3, p4, p5, p6};
  const int sz[7] = {SZ0, SZ1, SZ2, SZ3, SZ4, SZ5, SZ6};
  const int w = threadIdx.x >> 6;
  const int l = threadIdx.x & 63;
  if (w >= 7) return;
  const unsigned short* u = (const unsigned short*)ps[w];
  const int lim = sz[w] < 1024 ? sz[w] : 1024;
  int bad = 0;
  for (int j = l; j < lim; j += 64) {
    const unsigned e = (u[j] >> 7) & 0xFFu;
    if (e >= 0x8Eu) bad = 1;
  }
  const unsigned long long b = __ballot(bad);
  if (l == 0) flags[w] = (b != 0ULL) ? 1 : 0;
}

__global__ __launch_bounds__(256) void convert_kernel(
    const void* p0, const void* p1, const void* p2, const void* p3,
    const void* p4, const void* p5, const void* p6,
    const int* __restrict__ flags, __hip_bfloat16* __restrict__ dst) {
  const int gid = blockIdx.x * 256 + threadIdx.x;
  if (gid >= CTOT) return;
  int t, local;
  const void* p;
  if (gid < CU1)      { t = 0; local = gid - CU0; p = p0; }
  else if (gid < CU2) { t = 1; local = gid - CU1; p = p1; }
  else if (gid < CU3) { t = 2; local = gid - CU2; p = p2; }
  else if (gid < CU4) { t = 3; local = gid - CU3; p = p3; }
  else if (gid < CU5) { t = 4; local = gid - CU4; p = p4; }
  else if (gid < CU6) { t = 5; local = gid - CU5; p = p5; }
  else                { t = 6; local = gid - CU6; p = p6; }
  __hip_bfloat16 v;
  if (flags[t])
    v = __float2bfloat16(((const float*)p)[local]);
  else
    v = ((const __hip_bfloat16*)p)[local];
  dst[gid] = v;
}

// ---------------------------------------------------------------------------
// m97-structure GEMM body for the two small projections (unchanged).
// ---------------------------------------------------------------------------
__device__ __forceinline__ void gemm_bt_body(
    const __hip_bfloat16* __restrict__ A, const __hip_bfloat16* __restrict__ Bw,
    const __hip_bfloat16* __restrict__ bias, float* __restrict__ C,
    int M, int N, int K, int bid,
    __hip_bfloat16* sA, __hip_bfloat16* sB) {
  const int tid = threadIdx.x;
  const int w = tid >> 6;
  const int l = tid & 63;
  const int ntiles = N >> 7;
  const int mt = bid / ntiles;
  const int nt = bid % ntiles;
  const int m0 = mt << 7;
  const int n0 = nt << 7;
  const int wm = (w >> 1) << 6;
  const int wn = (w & 1) << 6;
  const int r16 = l & 15;
  const int q = l >> 4;

  f32x4 acc[4][4] = {};

  const int srow_in = l >> 3;
  const int scol = (l & 7) << 3;

  for (int k0 = 0; k0 < K; k0 += 64) {
#pragma unroll
    for (int i = 0; i < 4; ++i) {
      const int c = (w << 2) + i;
      const int row = (c << 3) + srow_in;
      const __hip_bfloat16* gA = A + (size_t)(m0 + row) * K + k0 + scol;
      const __hip_bfloat16* gB = Bw + (size_t)(n0 + row) * K + k0 + scol;
      __builtin_amdgcn_global_load_lds(
          (const __attribute__((address_space(1))) void*)gA,
          (__attribute__((address_space(3))) void*)(sA + (c << 9) + (l << 3)),
          16, 0, 0);
      __builtin_amdgcn_global_load_lds(
          (const __attribute__((address_space(1))) void*)gB,
          (__attribute__((address_space(3))) void*)(sB + (c << 9) + (l << 3)),
          16, 0, 0);
    }
    __syncthreads();

#pragma unroll
    for (int kk = 0; kk < 2; ++kk) {
      const int kc = (kk << 5) + (q << 3);
      short8 af[4], bf[4];
#pragma unroll
      for (int mi = 0; mi < 4; ++mi)
        af[mi] = *(const short8*)(sA + (wm + (mi << 4) + r16) * 64 + kc);
#pragma unroll
      for (int ni = 0; ni < 4; ++ni)
        bf[ni] = *(const short8*)(sB + (wn + (ni << 4) + r16) * 64 + kc);
#pragma unroll
      for (int mi = 0; mi < 4; ++mi)
#pragma unroll
        for (int ni = 0; ni < 4; ++ni)
          acc[mi][ni] = __builtin_amdgcn_mfma_f32_16x16x32_bf16(
              af[mi], bf[ni], acc[mi][ni], 0, 0, 0);
    }
    __syncthreads();
  }

#pragma unroll
  for (int ni = 0; ni < 4; ++ni) {
    const int col = n0 + wn + (ni << 4) + r16;
    const float bc = bias ? __bfloat162float(bias[col]) : 0.0f;
#pragma unroll
    for (int mi = 0; mi < 4; ++mi) {
      const int rowb = m0 + wm + (mi << 4) + (q << 2);
#pragma unroll
      for (int i = 0; i < 4; ++i)
        C[(size_t)(rowb + i) * N + col] = acc[mi][ni][i] + bc;
    }
  }
}

__global__ __launch_bounds__(256) void proj_kernel(
    const __hip_bfloat16* __restrict__ enc, const __hip_bfloat16* __restrict__ Wenc,
    const __hip_bfloat16* __restrict__ benc,
    const __hip_bfloat16* __restrict__ dec, const __hip_bfloat16* __restrict__ Wdec,
    float* __restrict__ Pe, float* __restrict__ Pd) {
  __shared__ __align__(16) __hip_bfloat16 sA[128 * 64];
  __shared__ __align__(16) __hip_bfloat16 sB[128 * 64];
  if (blockIdx.x < 32)
    gemm_bt_body(enc, Wenc, benc, Pe, 1024, 512, 512, blockIdx.x, sA, sB);
  else
    gemm_bt_body(dec, Wdec, nullptr, Pd, 256, 512, 512, blockIdx.x - 32, sA, sB);
}

// ---------------------------------------------------------------------------
// Main fused GEMM. grid = 512 blocks (BM=128), 1024 threads (16 waves,
// 4/SIMD). Wave grid 2(M)x8(N), wave-tile 64x64, acc = 4 x f32x16.
// 64 iters = 2 nt-passes (BN=512) x 32 k-steps (BK=16, 32x32x16 MFMA).
// Per iter/thread: 1 global_load_lds (stage next sB), then per wave
// 4 ds_read_b128 + 4 MFMA; one __syncthreads per iter (drain covered by
// the ~550cy compute phase). C-store at each nt boundary.
// ---------------------------------------------------------------------------
__global__ __launch_bounds__(1024, 4) void gemm_joint(
    const float* __restrict__ Pe, const float* __restrict__ Pd,
    const __hip_bfloat16* __restrict__ Bw,
    const __hip_bfloat16* __restrict__ bias, float* __restrict__ out) {
  __shared__ __align__(16) __hip_bfloat16 sH[128 * 512];  // 128 KB
  __shared__ __align__(16) __hip_bfloat16 sB[2 * 8192];   // 2 x 16 KB, [buf][c][n]

  const int t = threadIdx.x;
  const int w = t >> 6;
  const int l = t & 63;
  const int l31 = l & 31;
  const int q2 = l >> 5;
  const int m0 = blockIdx.x << 7;

  // STAGE: sB[buf] <- W_out tile (nt = iter>>5, ks = iter&31), K-major:
  // slot t: c = t>>9 (k-half), n = t&511. Linear LDS dest; no swizzle needed.
  auto stage = [&](int iter, int buf) {
    const int n0 = (iter >> 5) << 9;
    const int k0 = (iter & 31) << 4;
    const int n = t & 511;
    const int c = t >> 9;
    const __hip_bfloat16* src = Bw + (size_t)(n0 + n) * 512 + k0 + (c << 3);
    __builtin_amdgcn_global_load_lds(
        (const __attribute__((address_space(1))) void*)src,
        (__attribute__((address_space(3))) void*)(sB + (buf << 13) + (t << 3)),
        16, 0, 0);
  };

  // Prologue: first B-tile in flight while tanh phase runs.
  stage(0, 0);

  // Phase 1: sH = tanh(Pe[e] + Pd[d]), each (row, chunk) exactly once.
  // r = t&127 (H row), seg = t>>7 (64-col segment). e = 2*blk + (r>>6),
  // d = (blk>>7)*64 + (r&63).  Chunk c stored at c ^ (r&63).
  {
    const int r = t & 127;
    const int seg = t >> 7;
    const int e = (blockIdx.x << 1) + (r >> 6);
    const int d = ((blockIdx.x >> 7) << 6) | (r & 63);
    const float* pe = Pe + (size_t)e * 512 + (seg << 6);
    const float* pd = Pd + (size_t)d * 512 + (seg << 6);
    const int swr = r & 63;
#pragma unroll
    for (int i = 0; i < 8; ++i) {
      const int cc = (seg << 3) + i;            // chunk index 0..63
      const f32x4 a0 = *(const f32x4*)(pe + (i << 3));
      const f32x4 a1 = *(const f32x4*)(pe + (i << 3) + 4);
      const f32x4 b0 = *(const f32x4*)(pd + (i << 3));
      const f32x4 b1 = *(const f32x4*)(pd + (i << 3) + 4);
      short8 hv;
#pragma unroll
      for (int jj = 0; jj < 4; ++jj) {
        float s = a0[jj] + b0[jj];
        float tv = 1.0f - 2.0f / (__expf(2.0f * s) + 1.0f);
        __hip_bfloat16 hb = __float2bfloat16(tv);
        hv[jj] = *(const short*)&hb;
        s = a1[jj] + b1[jj];
        tv = 1.0f - 2.0f / (__expf(2.0f * s) + 1.0f);
        hb = __float2bfloat16(tv);
        hv[4 + jj] = *(const short*)&hb;
      }
      *(short8*)(sH + (r << 9) + ((cc ^ swr) << 3)) = hv;
    }
  }
  __syncthreads();  // drains stage(0) vmcnt + sH lgkm

  const int wm = (w >> 3) << 6;   // 0 or 64 (M)
  const int wn = (w & 7) << 6;    // 0..448 (N within nt-pass)
  f32x16 acc[2][2] = {};

  // Hoisted sH read params: row, row-base, per-row XOR (wm&63 == 0).
  int arow[2], aswz[2];
#pragma unroll
  for (int mi = 0; mi < 2; ++mi) {
    const int row = wm + (mi << 5) + l31;
    arow[mi] = row << 9;
    aswz[mi] = row & 63;
  }
  // sB read offsets (elements): [c=q2][n], iter-invariant.
  int boff[2];
#pragma unroll
  for (int ni = 0; ni < 2; ++ni)
    boff[ni] = (q2 << 12) + ((wn + (ni << 5) + l31) << 3);

  int buf = 0;
  for (int iter = 0; iter < 64; ++iter) {
    if (iter < 63) stage(iter + 1, buf ^ 1);

    const int cb = ((iter & 31) << 1) + q2;     // chunk = 2*ks + q2
    short8 af[2], bf[2];
#pragma unroll
    for (int mi = 0; mi < 2; ++mi)
      af[mi] = *(const short8*)(sH + arow[mi] + ((cb ^ aswz[mi]) << 3));
#pragma unroll
    for (int ni = 0; ni < 2; ++ni)
      bf[ni] = *(const short8*)(sB + (buf << 13) + boff[ni]);
#pragma unroll
    for (int mi = 0; mi < 2; ++mi)
#pragma unroll
      for (int ni = 0; ni < 2; ++ni)
        acc[mi][ni] = __builtin_amdgcn_mfma_f32_32x32x16_bf16(
            af[mi], bf[ni], acc[mi][ni], 0, 0, 0);

    if ((iter & 31) == 31) {
      // End of nt-pass: store 128x512 sub-tile, re-zero acc.
      // C/D layout (harness-verified R4): col=l&31, row=(r&3)+8*(r>>2)+4*q2.
      const int n0 = (iter >> 5) << 9;
#pragma unroll
      for (int ni = 0; ni < 2; ++ni) {
        const int col = n0 + wn + (ni << 5) + l31;
        const float bc = __bfloat162float(bias[col]);
#pragma unroll
        for (int mi = 0; mi < 2; ++mi) {
#pragma unroll
          for (int rr = 0; rr < 16; ++rr) {
            const int row = m0 + wm + (mi << 5) + (rr & 3) + ((rr >> 2) << 3) +
                            (q2 << 2);
            out[(size_t)row * 1024 + col] = acc[mi][ni][rr] + bc;
          }
          acc[mi][ni] = (f32x16){};
        }
      }
    }

    __syncthreads();  // next sB tile ready (loads were in flight ~550cy)
    buf ^= 1;
  }
}

// ---------------------------------------------------------------------------
extern "C" void kernel_launch(void* const* d_in, const int* in_sizes, int n_in,
                              void* d_out, int out_size, void* d_ws,
                              size_t ws_size, hipStream_t stream) {
  // ws layout: 0 flags (7 ints) | 256 bf16 copies (3.41MB) | 4MB Pe | 6MB Pd
  char* ws = (char*)d_ws;
  int* flags = (int*)ws;
  __hip_bfloat16* cp = (__hip_bfloat16*)(ws + 256);
  float* Pe = (float*)(ws + (4ull << 20));
  float* Pd = (float*)(ws + (6ull << 20));

  detect_kernel<<<dim3(1), dim3(512), 0, stream>>>(
      d_in[0], d_in[1], d_in[2], d_in[3], d_in[4], d_in[5], d_in[6], flags);
  convert_kernel<<<dim3((CTOT + 255) / 256), dim3(256), 0, stream>>>(
      d_in[0], d_in[1], d_in[2], d_in[3], d_in[4], d_in[5], d_in[6], flags, cp);

  const __hip_bfloat16* enc_c = cp + CU0;
  const __hip_bfloat16* dec_c = cp + CU1;
  const __hip_bfloat16* Wenc_c = cp + CU2;
  const __hip_bfloat16* benc_c = cp + CU3;
  const __hip_bfloat16* Wdec_c = cp + CU4;
  const __hip_bfloat16* Wout_c = cp + CU5;
  const __hip_bfloat16* bout_c = cp + CU6;

  proj_kernel<<<dim3(40), dim3(256), 0, stream>>>(enc_c, Wenc_c, benc_c,
                                                  dec_c, Wdec_c, Pe, Pd);
  gemm_joint<<<dim3(512), dim3(1024), 0, stream>>>(
      Pe, Pd, Wout_c, bout_c, (float*)d_out);
}

// Round 7
// 472.894 us; speedup vs baseline: 1.0940x; 1.0202x over previous
//
#include <hip/hip_runtime.h>
#include <hip/hip_bf16.h>

// RNN-T joint network. B=4 T=256 U=64 D=512 J=512 V=1024.
//   Pe = enc @ W_enc^T + b_enc   (1024 x 512)  fp32 in ws
//   Pd = dec @ W_dec^T           (256  x 512)  fp32 in ws
//   out[m,:] = tanh(Pe[m>>6] + Pd[(m>>14)*64 + (m&63)]) @ W_out^T + b_out
//
// gemm_joint (round-7): R6's counted-vmcnt pipeline with the stage()
// addressing bug fixed.
//   R6 FAILURE root cause: global_load_lds writes wave-uniform-base +
//   lane*16 ONLY (m104/m108). R6's dest had per-lane stride 32B -> half
//   of every sB tile landed at the wrong LDS address (absmax 54).
//   Fix: lane l of instr h covers row n = w*128 + h*32 + (l>>1), chunk
//   j = l&1; dest element = n*16 + j*8 == uniform + l*8 elems (16B) OK.
//   Global SOURCE stays per-lane (allowed): Bw + n*512 + ks*16 + j*8.
// Structure (unchanged from R6): BM=64, BN=1024 single pass, BK=16,
// 8 waves, wave-tile 64x128, 32x32x16 MFMA, sH 64KB full-K (tanh once,
// chunk c of row r at slot c^r -- measured 0-conflict in R5), sB dbuf
// 2x32KB row-major [n][16elem]; loop = {stage(ks+1); vmcnt(4); barrier;
// ds_read+8 MFMA; barrier} -- no vmcnt(0) until the last iter (T3/T4).
// Read-bank note: bf 8-lane phase hits 4 slots = 2-way = free (m136).

typedef __attribute__((ext_vector_type(8))) short short8;     // 8 bf16
typedef __attribute__((ext_vector_type(4))) float f32x4;
typedef __attribute__((ext_vector_type(16))) float f32x16;

#define SZ0 524288
#define SZ1 131072
#define SZ2 262144
#define SZ3 512
#define SZ4 262144
#define SZ5 524288
#define SZ6 1024
#define CU0 0
#define CU1 524288
#define CU2 655360
#define CU3 917504
#define CU4 918016
#define CU5 1180160
#define CU6 1704448
#define CTOT 1705472

// ---------------------------------------------------------------------------
// Runtime dtype detection (unchanged).
// ---------------------------------------------------------------------------
__global__ void detect_kernel(const void* p0, const void* p1, const void* p2,
                              const void* p3, const void* p4, const void* p5,
                              const void* p6, int* flags) {
  const void* ps[7] = {p0, p1, p2, p3, p4, p5, p6};
  const int sz[7] = {SZ0, SZ1, SZ2, SZ3, SZ4, SZ5, SZ6};
  const int w = threadIdx.x >> 6;
  const int l = threadIdx.x & 63;
  if (w >= 7) return;
  const unsigned short* u = (const unsigned short*)ps[w];
  const int lim = sz[w] < 1024 ? sz[w] : 1024;
  int bad = 0;
  for (int j = l; j < lim; j += 64) {
    const unsigned e = (u[j] >> 7) & 0xFFu;
    if (e >= 0x8Eu) bad = 1;
  }
  const unsigned long long b = __ballot(bad);
  if (l == 0) flags[w] = (b != 0ULL) ? 1 : 0;
}

__global__ __launch_bounds__(256) void convert_kernel(
    const void* p0, const void* p1, const void* p2, const void* p3,
    const void* p4, const void* p5, const void* p6,
    const int* __restrict__ flags, __hip_bfloat16* __restrict__ dst) {
  const int gid = blockIdx.x * 256 + threadIdx.x;
  if (gid >= CTOT) return;
  int t, local;
  const void* p;
  if (gid < CU1)      { t = 0; local = gid - CU0; p = p0; }
  else if (gid < CU2) { t = 1; local = gid - CU1; p = p1; }
  else if (gid < CU3) { t = 2; local = gid - CU2; p = p2; }
  else if (gid < CU4) { t = 3; local = gid - CU3; p = p3; }
  else if (gid < CU5) { t = 4; local = gid - CU4; p = p4; }
  else if (gid < CU6) { t = 5; local = gid - CU5; p = p5; }
  else                { t = 6; local = gid - CU6; p = p6; }
  __hip_bfloat16 v;
  if (flags[t])
    v = __float2bfloat16(((const float*)p)[local]);
  else
    v = ((const __hip_bfloat16*)p)[local];
  dst[gid] = v;
}

// ---------------------------------------------------------------------------
// m97-structure GEMM body for the two small projections (unchanged).
// ---------------------------------------------------------------------------
__device__ __forceinline__ void gemm_bt_body(
    const __hip_bfloat16* __restrict__ A, const __hip_bfloat16* __restrict__ Bw,
    const __hip_bfloat16* __restrict__ bias, float* __restrict__ C,
    int M, int N, int K, int bid,
    __hip_bfloat16* sA, __hip_bfloat16* sB) {
  const int tid = threadIdx.x;
  const int w = tid >> 6;
  const int l = tid & 63;
  const int ntiles = N >> 7;
  const int mt = bid / ntiles;
  const int nt = bid % ntiles;
  const int m0 = mt << 7;
  const int n0 = nt << 7;
  const int wm = (w >> 1) << 6;
  const int wn = (w & 1) << 6;
  const int r16 = l & 15;
  const int q = l >> 4;

  f32x4 acc[4][4] = {};

  const int srow_in = l >> 3;
  const int scol = (l & 7) << 3;

  for (int k0 = 0; k0 < K; k0 += 64) {
#pragma unroll
    for (int i = 0; i < 4; ++i) {
      const int c = (w << 2) + i;
      const int row = (c << 3) + srow_in;
      const __hip_bfloat16* gA = A + (size_t)(m0 + row) * K + k0 + scol;
      const __hip_bfloat16* gB = Bw + (size_t)(n0 + row) * K + k0 + scol;
      __builtin_amdgcn_global_load_lds(
          (const __attribute__((address_space(1))) void*)gA,
          (__attribute__((address_space(3))) void*)(sA + (c << 9) + (l << 3)),
          16, 0, 0);
      __builtin_amdgcn_global_load_lds(
          (const __attribute__((address_space(1))) void*)gB,
          (__attribute__((address_space(3))) void*)(sB + (c << 9) + (l << 3)),
          16, 0, 0);
    }
    __syncthreads();

#pragma unroll
    for (int kk = 0; kk < 2; ++kk) {
      const int kc = (kk << 5) + (q << 3);
      short8 af[4], bf[4];
#pragma unroll
      for (int mi = 0; mi < 4; ++mi)
        af[mi] = *(const short8*)(sA + (wm + (mi << 4) + r16) * 64 + kc);
#pragma unroll
      for (int ni = 0; ni < 4; ++ni)
        bf[ni] = *(const short8*)(sB + (wn + (ni << 4) + r16) * 64 + kc);
#pragma unroll
      for (int mi = 0; mi < 4; ++mi)
#pragma unroll
        for (int ni = 0; ni < 4; ++ni)
          acc[mi][ni] = __builtin_amdgcn_mfma_f32_16x16x32_bf16(
              af[mi], bf[ni], acc[mi][ni], 0, 0, 0);
    }
    __syncthreads();
  }

#pragma unroll
  for (int ni = 0; ni < 4; ++ni) {
    const int col = n0 + wn + (ni << 4) + r16;
    const float bc = bias ? __bfloat162float(bias[col]) : 0.0f;
#pragma unroll
    for (int mi = 0; mi < 4; ++mi) {
      const int rowb = m0 + wm + (mi << 4) + (q << 2);
#pragma unroll
      for (int i = 0; i < 4; ++i)
        C[(size_t)(rowb + i) * N + col] = acc[mi][ni][i] + bc;
    }
  }
}

__global__ __launch_bounds__(256) void proj_kernel(
    const __hip_bfloat16* __restrict__ enc, const __hip_bfloat16* __restrict__ Wenc,
    const __hip_bfloat16* __restrict__ benc,
    const __hip_bfloat16* __restrict__ dec, const __hip_bfloat16* __restrict__ Wdec,
    float* __restrict__ Pe, float* __restrict__ Pd) {
  __shared__ __align__(16) __hip_bfloat16 sA[128 * 64];
  __shared__ __align__(16) __hip_bfloat16 sB[128 * 64];
  if (blockIdx.x < 32)
    gemm_bt_body(enc, Wenc, benc, Pe, 1024, 512, 512, blockIdx.x, sA, sB);
  else
    gemm_bt_body(dec, Wdec, nullptr, Pd, 256, 512, 512, blockIdx.x - 32, sA, sB);
}

// ---------------------------------------------------------------------------
// Main fused GEMM. grid = 1024 blocks (BM=64), 512 threads (8 waves),
// 1 WG/CU (128KB LDS). Waves span N: wn = w*128; wave-tile 64(M)x128(N),
// acc[2][4] f32x16. 32 iters (BK=16). Per iter/wave: 4 gload_lds (stage
// next, lane-contiguous dest), 6 ds_read_b128, 8 MFMA, 2 raw barriers,
// counted vmcnt(4) -- NO vmcnt(0) until last iter.
// ---------------------------------------------------------------------------
__global__ __launch_bounds__(512, 2) void gemm_joint(
    const float* __restrict__ Pe, const float* __restrict__ Pd,
    const __hip_bfloat16* __restrict__ Bw,
    const __hip_bfloat16* __restrict__ bias, float* __restrict__ out) {
  __shared__ __align__(16) __hip_bfloat16 sH[64 * 512];   // 64 KB
  __shared__ __align__(16) __hip_bfloat16 sB[2 * 16384];  // 2 x 32 KB, [n][16e]

  const int t = threadIdx.x;
  const int w = t >> 6;
  const int l = t & 63;
  const int l31 = l & 31;
  const int q2 = l >> 5;
  const int m0 = blockIdx.x << 6;

  // STAGE: sB[buf] <- W_out[:, ks*16 .. +16), row-major [n][16 elems].
  // HW rule (m104): LDS dest must be wave-uniform + lane*16. Instr h of
  // wave w: lane l -> row n = w*128 + h*32 + (l>>1), chunk j = l&1;
  // dest elem = n*16 + j*8 = (w*4+h)*512 + l*8  (lane-contiguous 16B).
  // Global source is per-lane (allowed).
  auto stage = [&](int ks, int bufbit) {
#pragma unroll
    for (int h = 0; h < 4; ++h) {
      const int n = (w << 7) + (h << 5) + (l >> 1);
      const __hip_bfloat16* src =
          Bw + (size_t)n * 512 + (ks << 4) + ((l & 1) << 3);
      __builtin_amdgcn_global_load_lds(
          (const __attribute__((address_space(1))) void*)src,
          (__attribute__((address_space(3))) void*)(
              sB + (bufbit << 14) + ((((w << 2) + h) << 9) + (l << 3))),
          16, 0, 0);
    }
  };

  // Prologue: first B-tile in flight while the tanh phase runs.
  stage(0, 0);

  // Phase 1: sH = tanh(Pe[e] + Pd[d]); e = blockIdx (uniform), one Pe row
  // broadcast over the block's 64 H-rows; d = (blk>>8)*64 + r.
  // Thread: row r = l, column segment seg = w (64 cols = 8 chunks).
  {
    const int r = l;
    const int seg = w;
    const int d = ((blockIdx.x >> 8) << 6) | r;
    const float* pe = Pe + (size_t)blockIdx.x * 512 + (seg << 6);
    const float* pd = Pd + (size_t)d * 512 + (seg << 6);
#pragma unroll
    for (int i = 0; i < 8; ++i) {
      const int cc = (seg << 3) + i;            // chunk index 0..63
      const f32x4 a0 = *(const f32x4*)(pe + (i << 3));
      const f32x4 a1 = *(const f32x4*)(pe + (i << 3) + 4);
      const f32x4 b0 = *(const f32x4*)(pd + (i << 3));
      const f32x4 b1 = *(const f32x4*)(pd + (i << 3) + 4);
      short8 hv;
#pragma unroll
      for (int jj = 0; jj < 4; ++jj) {
        float s = a0[jj] + b0[jj];
        float tv = 1.0f - 2.0f / (__expf(2.0f * s) + 1.0f);
        __hip_bfloat16 hb = __float2bfloat16(tv);
        hv[jj] = *(const short*)&hb;
        s = a1[jj] + b1[jj];
        tv = 1.0f - 2.0f / (__expf(2.0f * s) + 1.0f);
        hb = __float2bfloat16(tv);
        hv[4 + jj] = *(const short*)&hb;
      }
      *(short8*)(sH + (r << 9) + ((cc ^ r) << 3)) = hv;
    }
  }
  __syncthreads();  // full drain once: stage(0) + sH writes both landed

  const int wn = w << 7;          // wave N-origin: 0..896
  f32x16 acc[2][4] = {};

  for (int ks = 0; ks < 32; ++ks) {
    const int bufbit = ks & 1;
    if (ks < 31) {
      stage(ks + 1, bufbit ^ 1);
      asm volatile("s_waitcnt vmcnt(4)" ::: "memory");  // stage(ks) landed
    } else {
      asm volatile("s_waitcnt vmcnt(0)" ::: "memory");
    }
    __builtin_amdgcn_sched_barrier(0);
    __builtin_amdgcn_s_barrier();        // everyone's stage(ks) landed
    __builtin_amdgcn_sched_barrier(0);

    const int cb = (ks << 1) + q2;       // sH chunk for this k-step
    short8 af[2];
#pragma unroll
    for (int mi = 0; mi < 2; ++mi) {
      const int r = (mi << 5) + l31;
      af[mi] = *(const short8*)(sH + (r << 9) + ((cb ^ r) << 3));
    }
    short8 bf[4];
#pragma unroll
    for (int ni = 0; ni < 4; ++ni)
      bf[ni] = *(const short8*)(sB + (bufbit << 14) +
                                ((wn + (ni << 5) + l31) << 4) + (q2 << 3));
#pragma unroll
    for (int mi = 0; mi < 2; ++mi)
#pragma unroll
      for (int ni = 0; ni < 4; ++ni)
        acc[mi][ni] = __builtin_amdgcn_mfma_f32_32x32x16_bf16(
            af[mi], bf[ni], acc[mi][ni], 0, 0, 0);

    __builtin_amdgcn_sched_barrier(0);
    __builtin_amdgcn_s_barrier();        // readers done before next DMA write
    __builtin_amdgcn_sched_barrier(0);
  }

  // Epilogue: C/D layout (harness-verified R4/R5):
  // col = l&31, row = (rr&3) + 8*(rr>>2) + 4*q2.
#pragma unroll
  for (int ni = 0; ni < 4; ++ni) {
    const int col = wn + (ni << 5) + l31;
    const float bc = __bfloat162float(bias[col]);
#pragma unroll
    for (int mi = 0; mi < 2; ++mi) {
#pragma unroll
      for (int rr = 0; rr < 16; ++rr) {
        const int row = m0 + (mi << 5) + (rr & 3) + ((rr >> 2) << 3) + (q2 << 2);
        out[(size_t)row * 1024 + col] = acc[mi][ni][rr] + bc;
      }
    }
  }
}

// ---------------------------------------------------------------------------
extern "C" void kernel_launch(void* const* d_in, const int* in_sizes, int n_in,
                              void* d_out, int out_size, void* d_ws,
                              size_t ws_size, hipStream_t stream) {
  // ws layout: 0 flags (7 ints) | 256 bf16 copies (3.41MB) | 4MB Pe | 6MB Pd
  char* ws = (char*)d_ws;
  int* flags = (int*)ws;
  __hip_bfloat16* cp = (__hip_bfloat16*)(ws + 256);
  float* Pe = (float*)(ws + (4ull << 20));
  float* Pd = (float*)(ws + (6ull << 20));

  detect_kernel<<<dim3(1), dim3(512), 0, stream>>>(
      d_in[0], d_in[1], d_in[2], d_in[3], d_in[4], d_in[5], d_in[6], flags);
  convert_kernel<<<dim3((CTOT + 255) / 256), dim3(256), 0, stream>>>(
      d_in[0], d_in[1], d_in[2], d_in[3], d_in[4], d_in[5], d_in[6], flags, cp);

  const __hip_bfloat16* enc_c = cp + CU0;
  const __hip_bfloat16* dec_c = cp + CU1;
  const __hip_bfloat16* Wenc_c = cp + CU2;
  const __hip_bfloat16* benc_c = cp + CU3;
  const __hip_bfloat16* Wdec_c = cp + CU4;
  const __hip_bfloat16* Wout_c = cp + CU5;
  const __hip_bfloat16* bout_c = cp + CU6;

  proj_kernel<<<dim3(40), dim3(256), 0, stream>>>(enc_c, Wenc_c, benc_c,
                                                  dec_c, Wdec_c, Pe, Pd);
  gemm_joint<<<dim3(1024), dim3(512), 0, stream>>>(
      Pe, Pd, Wout_c, bout_c, (float*)d_out);
}

// Round 8
// 445.529 us; speedup vs baseline: 1.1612x; 1.0614x over previous
//
#include <hip/hip_runtime.h>
#include <hip/hip_bf16.h>

// RNN-T joint network. B=4 T=256 U=64 D=512 J=512 V=1024.
//   Pe = enc @ W_enc^T + b_enc   (1024 x 512)  fp32 in ws
//   Pd = dec @ W_dec^T           (256  x 512)  fp32 in ws
//   out[m,:] = tanh(Pe[m>>6] + Pd[(m>>14)*64 + (m&63)]) @ W_out^T + b_out
//
// gemm_joint (round-8): A-FRAGMENTS IN REGISTERS, no sA/sH at all.
//   R2-R7 lesson: every 1-WG/CU variant (R2/R5/R7) stalls at 196-286us;
//   the only 2-WG variant (R3) is best (<=172us). The 32x32x16 A-fragment
//   is lane-local (8 contiguous k of one row) == one f32x8 Pe + f32x8 Pd
//   + 8 tanh in regs. So: no H in LDS, recompute factor only x2 (2 N-waves).
//   LDS = sB only: BM=128, BN=256, BK=64 (128B rows -> 8-slot XOR swizzle),
//   dbuf 2x32KB = 64KB/WG -> 2 WG/CU at 512 thr (launch_bounds(512,4)).
//   Per tile/CU: MFMA 1033cy, stage 500cy coalesced, trans ~1000cy, VALU
//   ~500cy -- balanced, overlapped by 4 waves/SIMD.
//   R7 lesson kept: stage dest = wave-uniform + lane*16 (rule m104);
//   pre-swizzled SOURCE + swizzled READ (rule #21, R3-verified pattern).

typedef __attribute__((ext_vector_type(8))) short short8;     // 8 bf16
typedef __attribute__((ext_vector_type(4))) float f32x4;
typedef __attribute__((ext_vector_type(8))) float f32x8;
typedef __attribute__((ext_vector_type(16))) float f32x16;

#define SZ0 524288
#define SZ1 131072
#define SZ2 262144
#define SZ3 512
#define SZ4 262144
#define SZ5 524288
#define SZ6 1024
#define CU0 0
#define CU1 524288
#define CU2 655360
#define CU3 917504
#define CU4 918016
#define CU5 1180160
#define CU6 1704448
#define CTOT 1705472

// ---------------------------------------------------------------------------
// Runtime dtype detection (unchanged).
// ---------------------------------------------------------------------------
__global__ void detect_kernel(const void* p0, const void* p1, const void* p2,
                              const void* p3, const void* p4, const void* p5,
                              const void* p6, int* flags) {
  const void* ps[7] = {p0, p1, p2, p3, p4, p5, p6};
  const int sz[7] = {SZ0, SZ1, SZ2, SZ3, SZ4, SZ5, SZ6};
  const int w = threadIdx.x >> 6;
  const int l = threadIdx.x & 63;
  if (w >= 7) return;
  const unsigned short* u = (const unsigned short*)ps[w];
  const int lim = sz[w] < 1024 ? sz[w] : 1024;
  int bad = 0;
  for (int j = l; j < lim; j += 64) {
    const unsigned e = (u[j] >> 7) & 0xFFu;
    if (e >= 0x8Eu) bad = 1;
  }
  const unsigned long long b = __ballot(bad);
  if (l == 0) flags[w] = (b != 0ULL) ? 1 : 0;
}

__global__ __launch_bounds__(256) void convert_kernel(
    const void* p0, const void* p1, const void* p2, const void* p3,
    const void* p4, const void* p5, const void* p6,
    const int* __restrict__ flags, __hip_bfloat16* __restrict__ dst) {
  const int gid = blockIdx.x * 256 + threadIdx.x;
  if (gid >= CTOT) return;
  int t, local;
  const void* p;
  if (gid < CU1)      { t = 0; local = gid - CU0; p = p0; }
  else if (gid < CU2) { t = 1; local = gid - CU1; p = p1; }
  else if (gid < CU3) { t = 2; local = gid - CU2; p = p2; }
  else if (gid < CU4) { t = 3; local = gid - CU3; p = p3; }
  else if (gid < CU5) { t = 4; local = gid - CU4; p = p4; }
  else if (gid < CU6) { t = 5; local = gid - CU5; p = p5; }
  else                { t = 6; local = gid - CU6; p = p6; }
  __hip_bfloat16 v;
  if (flags[t])
    v = __float2bfloat16(((const float*)p)[local]);
  else
    v = ((const __hip_bfloat16*)p)[local];
  dst[gid] = v;
}

// ---------------------------------------------------------------------------
// m97-structure GEMM body for the two small projections (unchanged).
// ---------------------------------------------------------------------------
__device__ __forceinline__ void gemm_bt_body(
    const __hip_bfloat16* __restrict__ A, const __hip_bfloat16* __restrict__ Bw,
    const __hip_bfloat16* __restrict__ bias, float* __restrict__ C,
    int M, int N, int K, int bid,
    __hip_bfloat16* sA, __hip_bfloat16* sB) {
  const int tid = threadIdx.x;
  const int w = tid >> 6;
  const int l = tid & 63;
  const int ntiles = N >> 7;
  const int mt = bid / ntiles;
  const int nt = bid % ntiles;
  const int m0 = mt << 7;
  const int n0 = nt << 7;
  const int wm = (w >> 1) << 6;
  const int wn = (w & 1) << 6;
  const int r16 = l & 15;
  const int q = l >> 4;

  f32x4 acc[4][4] = {};

  const int srow_in = l >> 3;
  const int scol = (l & 7) << 3;

  for (int k0 = 0; k0 < K; k0 += 64) {
#pragma unroll
    for (int i = 0; i < 4; ++i) {
      const int c = (w << 2) + i;
      const int row = (c << 3) + srow_in;
      const __hip_bfloat16* gA = A + (size_t)(m0 + row) * K + k0 + scol;
      const __hip_bfloat16* gB = Bw + (size_t)(n0 + row) * K + k0 + scol;
      __builtin_amdgcn_global_load_lds(
          (const __attribute__((address_space(1))) void*)gA,
          (__attribute__((address_space(3))) void*)(sA + (c << 9) + (l << 3)),
          16, 0, 0);
      __builtin_amdgcn_global_load_lds(
          (const __attribute__((address_space(1))) void*)gB,
          (__attribute__((address_space(3))) void*)(sB + (c << 9) + (l << 3)),
          16, 0, 0);
    }
    __syncthreads();

#pragma unroll
    for (int kk = 0; kk < 2; ++kk) {
      const int kc = (kk << 5) + (q << 3);
      short8 af[4], bf[4];
#pragma unroll
      for (int mi = 0; mi < 4; ++mi)
        af[mi] = *(const short8*)(sA + (wm + (mi << 4) + r16) * 64 + kc);
#pragma unroll
      for (int ni = 0; ni < 4; ++ni)
        bf[ni] = *(const short8*)(sB + (wn + (ni << 4) + r16) * 64 + kc);
#pragma unroll
      for (int mi = 0; mi < 4; ++mi)
#pragma unroll
        for (int ni = 0; ni < 4; ++ni)
          acc[mi][ni] = __builtin_amdgcn_mfma_f32_16x16x32_bf16(
              af[mi], bf[ni], acc[mi][ni], 0, 0, 0);
    }
    __syncthreads();
  }

#pragma unroll
  for (int ni = 0; ni < 4; ++ni) {
    const int col = n0 + wn + (ni << 4) + r16;
    const float bc = bias ? __bfloat162float(bias[col]) : 0.0f;
#pragma unroll
    for (int mi = 0; mi < 4; ++mi) {
      const int rowb = m0 + wm + (mi << 4) + (q << 2);
#pragma unroll
      for (int i = 0; i < 4; ++i)
        C[(size_t)(rowb + i) * N + col] = acc[mi][ni][i] + bc;
    }
  }
}

__global__ __launch_bounds__(256) void proj_kernel(
    const __hip_bfloat16* __restrict__ enc, const __hip_bfloat16* __restrict__ Wenc,
    const __hip_bfloat16* __restrict__ benc,
    const __hip_bfloat16* __restrict__ dec, const __hip_bfloat16* __restrict__ Wdec,
    float* __restrict__ Pe, float* __restrict__ Pd) {
  __shared__ __align__(16) __hip_bfloat16 sA[128 * 64];
  __shared__ __align__(16) __hip_bfloat16 sB[128 * 64];
  if (blockIdx.x < 32)
    gemm_bt_body(enc, Wenc, benc, Pe, 1024, 512, 512, blockIdx.x, sA, sB);
  else
    gemm_bt_body(dec, Wdec, nullptr, Pd, 256, 512, 512, blockIdx.x - 32, sA, sB);
}

// ---------------------------------------------------------------------------
// Main fused GEMM. grid = 2048 blocks (512 mb x 4 nb), 512 threads (8 waves),
// 2 WG/CU (64KB LDS, <=128 VGPR). Wave grid 4(M)x2(N), wave-tile 32x128.
// 8 K-tiles (BK=64), 4 k-steps each. A-fragment computed in registers per
// k-step: f32x8 Pe (wave-uniform row) + f32x8 Pd (lane row) -> 8 tanh ->
// short8. B staged via gload_lds into swizzled sB, dbuf, counted vmcnt(4).
// ---------------------------------------------------------------------------
__global__ __launch_bounds__(512, 4) void gemm_joint(
    const float* __restrict__ Pe, const float* __restrict__ Pd,
    const __hip_bfloat16* __restrict__ Bw,
    const __hip_bfloat16* __restrict__ bias, float* __restrict__ out) {
  __shared__ __align__(16) __hip_bfloat16 sB[2][256 * 64];  // 2 x 32 KB

  const int t = threadIdx.x;
  const int w = t >> 6;
  const int l = t & 63;
  const int l31 = l & 31;
  const int q2 = l >> 5;
  const int mb = blockIdx.x >> 2;
  const int nb = blockIdx.x & 3;
  const int m0 = mb << 7;
  const int n0 = nb << 8;

  // STAGE sB[b] <- W_out[n0..n0+256][kt*64..+64], row-major [256][64],
  // chunk c of row r holds source chunk c^(r&7) (read applies same XOR).
  // Dest elem = h*4096 + t*8 (wave-uniform + lane*16B, rule m104 OK).
  auto stage = [&](int kt, int b) {
    const int r_ = t >> 3;
    const int c_ = t & 7;
#pragma unroll
    for (int h = 0; h < 4; ++h) {
      const int r = (h << 6) + r_;
      const __hip_bfloat16* src =
          Bw + (size_t)(n0 + r) * 512 + (kt << 6) + ((c_ ^ (r & 7)) << 3);
      __builtin_amdgcn_global_load_lds(
          (const __attribute__((address_space(1))) void*)src,
          (__attribute__((address_space(3))) void*)(
              &sB[b][0] + (h << 12) + (t << 3)),
          16, 0, 0);
    }
  };

  const int wm = (w >> 1) << 5;   // 0,32,64,96 (M)
  const int wn = (w & 1) << 7;    // 0 or 128 (N)

  // Pe row is uniform per wave (wm aligned 32, 32 rows stay in one 64-group).
  const float* peRow = Pe + (size_t)((m0 + wm) >> 6) * 512;
  const int d = (((m0 >> 14) << 6) | ((wm + l31) & 63));
  const float* pdRow = Pd + (size_t)d * 512;

  f32x16 acc[4] = {};

  stage(0, 0);

  for (int kt = 0; kt < 8; ++kt) {
    const int b = kt & 1;
    if (kt < 7) {
      stage(kt + 1, b ^ 1);
      asm volatile("s_waitcnt vmcnt(4)" ::: "memory");  // stage(kt) landed
    } else {
      asm volatile("s_waitcnt vmcnt(0)" ::: "memory");
    }
    __builtin_amdgcn_sched_barrier(0);
    __builtin_amdgcn_s_barrier();
    __builtin_amdgcn_sched_barrier(0);

#pragma unroll
    for (int j = 0; j < 4; ++j) {
      // A-fragment in registers: rows wm+l31, k = kt*64 + j*16 + q2*8 (+0..7)
      const int kk = (kt << 6) + (j << 4) + (q2 << 3);
      const f32x8 pe8 = *(const f32x8*)(peRow + kk);
      const f32x8 pd8 = *(const f32x8*)(pdRow + kk);
      short8 af;
#pragma unroll
      for (int x = 0; x < 8; ++x) {
        const float s = pe8[x] + pd8[x];
        const float u = __expf(2.0f * s);
        const float tv = 1.0f - 2.0f * __builtin_amdgcn_rcpf(u + 1.0f);
        const __hip_bfloat16 hb = __float2bfloat16(tv);
        af[x] = *(const short*)&hb;
      }
      // B fragments from swizzled sB: row = wn + ni*32 + l31, chunk 2j+q2.
      const int c = (j << 1) + q2;
      short8 bf[4];
#pragma unroll
      for (int ni = 0; ni < 4; ++ni) {
        const int row = wn + (ni << 5) + l31;
        bf[ni] = *(const short8*)(&sB[b][0] + (row << 6) +
                                  ((c ^ (row & 7)) << 3));
      }
#pragma unroll
      for (int ni = 0; ni < 4; ++ni)
        acc[ni] = __builtin_amdgcn_mfma_f32_32x32x16_bf16(
            af, bf[ni], acc[ni], 0, 0, 0);
    }

    __builtin_amdgcn_sched_barrier(0);
    __builtin_amdgcn_s_barrier();   // all reads of sB[b] done before next
    __builtin_amdgcn_sched_barrier(0);  // iter's stage overwrites it
  }

  // Epilogue: C/D layout (harness-verified R4/R5/R7):
  // col = l&31, row = (rr&3) + 8*(rr>>2) + 4*q2.
#pragma unroll
  for (int ni = 0; ni < 4; ++ni) {
    const int col = n0 + wn + (ni << 5) + l31;
    const float bc = __bfloat162float(bias[col]);
#pragma unroll
    for (int rr = 0; rr < 16; ++rr) {
      const int row = m0 + wm + (rr & 3) + ((rr >> 2) << 3) + (q2 << 2);
      out[(size_t)row * 1024 + col] = acc[ni][rr] + bc;
    }
  }
}

// ---------------------------------------------------------------------------
extern "C" void kernel_launch(void* const* d_in, const int* in_sizes, int n_in,
                              void* d_out, int out_size, void* d_ws,
                              size_t ws_size, hipStream_t stream) {
  // ws layout: 0 flags (7 ints) | 256 bf16 copies (3.41MB) | 4MB Pe | 6MB Pd
  char* ws = (char*)d_ws;
  int* flags = (int*)ws;
  __hip_bfloat16* cp = (__hip_bfloat16*)(ws + 256);
  float* Pe = (float*)(ws + (4ull << 20));
  float* Pd = (float*)(ws + (6ull << 20));

  detect_kernel<<<dim3(1), dim3(512), 0, stream>>>(
      d_in[0], d_in[1], d_in[2], d_in[3], d_in[4], d_in[5], d_in[6], flags);
  convert_kernel<<<dim3((CTOT + 255) / 256), dim3(256), 0, stream>>>(
      d_in[0], d_in[1], d_in[2], d_in[3], d_in[4], d_in[5], d_in[6], flags, cp);

  const __hip_bfloat16* enc_c = cp + CU0;
  const __hip_bfloat16* dec_c = cp + CU1;
  const __hip_bfloat16* Wenc_c = cp + CU2;
  const __hip_bfloat16* benc_c = cp + CU3;
  const __hip_bfloat16* Wdec_c = cp + CU4;
  const __hip_bfloat16* Wout_c = cp + CU5;
  const __hip_bfloat16* bout_c = cp + CU6;

  proj_kernel<<<dim3(40), dim3(256), 0, stream>>>(enc_c, Wenc_c, benc_c,
                                                  dec_c, Wdec_c, Pe, Pd);
  gemm_joint<<<dim3(2048), dim3(512), 0, stream>>>(
      Pe, Pd, Wout_c, bout_c, (float*)d_out);
}

// Round 9
// 423.443 us; speedup vs baseline: 1.2218x; 1.0522x over previous
//
#include <hip/hip_runtime.h>
#include <hip/hip_bf16.h>

// RNN-T joint network. B=4 T=256 U=64 D=512 J=512 V=1024.
//   Pe = enc @ W_enc^T + b_enc   (1024 x 512)  fp32 in ws
//   Pd = dec @ W_dec^T           (256  x 512)  fp32 in ws
//   out[m,:] = tanh(Pe[m>>6] + Pd[(m>>14)*64 + (m&63)]) @ W_out^T + b_out
//
// gemm_joint (round-9): tanh x1 via LDS H, 2 WG/CU, coalesced staging.
//   R8 lesson: register-resident A forces tanh recompute = 1024/waveN >= 8
//   (acc VGPR bound) -> 110us of trans ops (VALUBusy 40%). H must be shared
//   via LDS. Prior sH attempts failed on (a) 1WG/CU (R5/R7), (b) gather
//   staging at small BK (R5/R7), (c) LDS BW (R3). All three fixed at once:
//   - W_out pre-transposed ONCE into WT[k/8][n][8] (1MB, 8 proj blocks).
//     BK=16 stage = 2 contiguous 16KB runs -> 4 coalesced gload_lds/thread.
//   - sH = 16KB K-QUARTER (64 rows x 128 k), chunk-major [cq][row][8]:
//     write AND read are lane-consecutive-16B -> no swizzle, no conflicts.
//     Refilled 4x/block; tanh computed exactly once (BN=1024, nb=1).
//   - LDS = 16 + 2x32 = 80KB exactly -> 2 WG/CU (R3 lesson).
//   - 8 waves, wave-tile 64x128 (af2+bf4 per 8 MFMA = 0.75KB/MFMA):
//     LDS/pair ~625cy vs MFMA 512cy -> ~82% ceiling. acc[2][4]=128 VGPR.
//   - R7-proven loop: stage(ks+1); vmcnt(4); s_barrier; ds+MFMA; s_barrier.
// Floor: max(MFMA 27.5us/0.8, HBM-write 43us) ~= 55-65us.

typedef __attribute__((ext_vector_type(8))) short short8;     // 8 bf16
typedef __attribute__((ext_vector_type(4))) float f32x4;
typedef __attribute__((ext_vector_type(8))) float f32x8;
typedef __attribute__((ext_vector_type(16))) float f32x16;

#define SZ0 524288
#define SZ1 131072
#define SZ2 262144
#define SZ3 512
#define SZ4 262144
#define SZ5 524288
#define SZ6 1024
#define CU0 0
#define CU1 524288
#define CU2 655360
#define CU3 917504
#define CU4 918016
#define CU5 1180160
#define CU6 1704448
#define CTOT 1705472

// ---------------------------------------------------------------------------
// Runtime dtype detection (unchanged).
// ---------------------------------------------------------------------------
__global__ void detect_kernel(const void* p0, const void* p1, const void* p2,
                              const void* p3, const void* p4, const void* p5,
                              const void* p6, int* flags) {
  const void* ps[7] = {p0, p1, p2, p3, p4, p5, p6};
  const int sz[7] = {SZ0, SZ1, SZ2, SZ3, SZ4, SZ5, SZ6};
  const int w = threadIdx.x >> 6;
  const int l = threadIdx.x & 63;
  if (w >= 7) return;
  const unsigned short* u = (const unsigned short*)ps[w];
  const int lim = sz[w] < 1024 ? sz[w] : 1024;
  int bad = 0;
  for (int j = l; j < lim; j += 64) {
    const unsigned e = (u[j] >> 7) & 0xFFu;
    if (e >= 0x8Eu) bad = 1;
  }
  const unsigned long long b = __ballot(bad);
  if (l == 0) flags[w] = (b != 0ULL) ? 1 : 0;
}

__global__ __launch_bounds__(256) void convert_kernel(
    const void* p0, const void* p1, const void* p2, const void* p3,
    const void* p4, const void* p5, const void* p6,
    const int* __restrict__ flags, __hip_bfloat16* __restrict__ dst) {
  const int gid = blockIdx.x * 256 + threadIdx.x;
  if (gid >= CTOT) return;
  int t, local;
  const void* p;
  if (gid < CU1)      { t = 0; local = gid - CU0; p = p0; }
  else if (gid < CU2) { t = 1; local = gid - CU1; p = p1; }
  else if (gid < CU3) { t = 2; local = gid - CU2; p = p2; }
  else if (gid < CU4) { t = 3; local = gid - CU3; p = p3; }
  else if (gid < CU5) { t = 4; local = gid - CU4; p = p4; }
  else if (gid < CU6) { t = 5; local = gid - CU5; p = p5; }
  else                { t = 6; local = gid - CU6; p = p6; }
  __hip_bfloat16 v;
  if (flags[t])
    v = __float2bfloat16(((const float*)p)[local]);
  else
    v = ((const __hip_bfloat16*)p)[local];
  dst[gid] = v;
}

// ---------------------------------------------------------------------------
// m97-structure GEMM body for the two small projections (unchanged).
// ---------------------------------------------------------------------------
__device__ __forceinline__ void gemm_bt_body(
    const __hip_bfloat16* __restrict__ A, const __hip_bfloat16* __restrict__ Bw,
    const __hip_bfloat16* __restrict__ bias, float* __restrict__ C,
    int M, int N, int K, int bid,
    __hip_bfloat16* sA, __hip_bfloat16* sB) {
  const int tid = threadIdx.x;
  const int w = tid >> 6;
  const int l = tid & 63;
  const int ntiles = N >> 7;
  const int mt = bid / ntiles;
  const int nt = bid % ntiles;
  const int m0 = mt << 7;
  const int n0 = nt << 7;
  const int wm = (w >> 1) << 6;
  const int wn = (w & 1) << 6;
  const int r16 = l & 15;
  const int q = l >> 4;

  f32x4 acc[4][4] = {};

  const int srow_in = l >> 3;
  const int scol = (l & 7) << 3;

  for (int k0 = 0; k0 < K; k0 += 64) {
#pragma unroll
    for (int i = 0; i < 4; ++i) {
      const int c = (w << 2) + i;
      const int row = (c << 3) + srow_in;
      const __hip_bfloat16* gA = A + (size_t)(m0 + row) * K + k0 + scol;
      const __hip_bfloat16* gB = Bw + (size_t)(n0 + row) * K + k0 + scol;
      __builtin_amdgcn_global_load_lds(
          (const __attribute__((address_space(1))) void*)gA,
          (__attribute__((address_space(3))) void*)(sA + (c << 9) + (l << 3)),
          16, 0, 0);
      __builtin_amdgcn_global_load_lds(
          (const __attribute__((address_space(1))) void*)gB,
          (__attribute__((address_space(3))) void*)(sB + (c << 9) + (l << 3)),
          16, 0, 0);
    }
    __syncthreads();

#pragma unroll
    for (int kk = 0; kk < 2; ++kk) {
      const int kc = (kk << 5) + (q << 3);
      short8 af[4], bf[4];
#pragma unroll
      for (int mi = 0; mi < 4; ++mi)
        af[mi] = *(const short8*)(sA + (wm + (mi << 4) + r16) * 64 + kc);
#pragma unroll
      for (int ni = 0; ni < 4; ++ni)
        bf[ni] = *(const short8*)(sB + (wn + (ni << 4) + r16) * 64 + kc);
#pragma unroll
      for (int mi = 0; mi < 4; ++mi)
#pragma unroll
        for (int ni = 0; ni < 4; ++ni)
          acc[mi][ni] = __builtin_amdgcn_mfma_f32_16x16x32_bf16(
              af[mi], bf[ni], acc[mi][ni], 0, 0, 0);
    }
    __syncthreads();
  }

#pragma unroll
  for (int ni = 0; ni < 4; ++ni) {
    const int col = n0 + wn + (ni << 4) + r16;
    const float bc = bias ? __bfloat162float(bias[col]) : 0.0f;
#pragma unroll
    for (int mi = 0; mi < 4; ++mi) {
      const int rowb = m0 + wm + (mi << 4) + (q << 2);
#pragma unroll
      for (int i = 0; i < 4; ++i)
        C[(size_t)(rowb + i) * N + col] = acc[mi][ni][i] + bc;
    }
  }
}

// proj blocks 0..39: Pe/Pd GEMMs. Blocks 40..47: W_out -> WT transpose,
// WT[(k>>3)*1024 + n][8] = W_out[n][k&~7 .. +8]  (chunk-major, 1MB).
__global__ __launch_bounds__(256) void proj_kernel(
    const __hip_bfloat16* __restrict__ enc, const __hip_bfloat16* __restrict__ Wenc,
    const __hip_bfloat16* __restrict__ benc,
    const __hip_bfloat16* __restrict__ dec, const __hip_bfloat16* __restrict__ Wdec,
    const __hip_bfloat16* __restrict__ Wout, __hip_bfloat16* __restrict__ WT,
    float* __restrict__ Pe, float* __restrict__ Pd) {
  __shared__ __align__(16) __hip_bfloat16 sA[128 * 64];
  __shared__ __align__(16) __hip_bfloat16 sB[128 * 64];
  if (blockIdx.x < 32) {
    gemm_bt_body(enc, Wenc, benc, Pe, 1024, 512, 512, blockIdx.x, sA, sB);
  } else if (blockIdx.x < 40) {
    gemm_bt_body(dec, Wdec, nullptr, Pd, 256, 512, 512, blockIdx.x - 32, sA, sB);
  } else {
    const int bid = blockIdx.x - 40;            // 0..7
#pragma unroll
    for (int i = 0; i < 32; ++i) {
      const int cid = (bid << 13) + (i << 8) + threadIdx.x;  // 0..65535
      const int n = cid >> 6;
      const int c = cid & 63;
      // read: 64 consecutive threads cover one row (1KB contiguous)
      *(short8*)(WT + (((size_t)c << 10) + n) * 8) =
          *(const short8*)(Wout + (size_t)n * 512 + (c << 3));
    }
  }
}

// ---------------------------------------------------------------------------
// Main fused GEMM. grid = 1024 blocks (BM=64, nb=1: BN=1024), 512 threads
// (8 waves, wave grid 1x8, wave-tile 64x128). 2 WG/CU (80KB LDS exactly).
// 32 stages (BK=16). Per stage/wave: 4 gload_lds (next, coalesced from WT),
// 2 af + 4 bf ds_read_b128, 8 MFMA, counted vmcnt(4), 2 raw barriers.
// sH = one K-quarter, refilled 4x (tanh exactly once per element).
// ---------------------------------------------------------------------------
__global__ __launch_bounds__(512, 2) void gemm_joint(
    const float* __restrict__ Pe, const float* __restrict__ Pd,
    const __hip_bfloat16* __restrict__ WT,
    const __hip_bfloat16* __restrict__ bias, float* __restrict__ out) {
  __shared__ __align__(16) __hip_bfloat16 sH[16 * 64 * 8];      // 16 KB
  __shared__ __align__(16) __hip_bfloat16 sB[2][2 * 1024 * 8];  // 2 x 32 KB

  const int t = threadIdx.x;
  const int w = t >> 6;
  const int l = t & 63;
  const int l31 = l & 31;
  const int q2 = l >> 5;
  const int m0 = blockIdx.x << 6;
  const int wn = w << 7;                 // wave N-origin 0..896

  // STAGE: sB[b] <- WT chunks {2ks, 2ks+1} (32KB contiguous). Dest slot
  // = h*512 + t -> byte = uniform + l*16 (rule m104 OK); source 16B slots
  // consecutive per lane -> 1KB contiguous per instr.
  auto stage = [&](int ks, int b) {
    const __hip_bfloat16* src = WT + ((size_t)ks << 14);  // ks*2048 slots*8
#pragma unroll
    for (int h = 0; h < 4; ++h) {
      const int slot = (h << 9) + t;
      __builtin_amdgcn_global_load_lds(
          (const __attribute__((address_space(1))) void*)(src + ((size_t)slot << 3)),
          (__attribute__((address_space(3))) void*)(&sB[b][0] + (slot << 3)),
          16, 0, 0);
    }
  };

  // FILL: sH[cq][r][0..8] = tanh(Pe[blk][q*128+cq*8+x] + Pd[d(r)][...]).
  // 1024 slots (64 r x 16 cq), 2 per thread. Writes lane-consecutive 16B.
  auto fillH = [&](int q) {
    const float* peB = Pe + (size_t)blockIdx.x * 512 + (q << 7);
    const int dbase = (blockIdx.x >> 8) << 6;
#pragma unroll
    for (int s2 = 0; s2 < 2; ++s2) {
      const int s = (s2 << 9) + t;       // 0..1023
      const int r = s & 63;
      const int cq = s >> 6;             // 0..15
      const f32x8 a = *(const f32x8*)(peB + (cq << 3));
      const f32x8 bv = *(const f32x8*)(Pd + (size_t)(dbase | r) * 512 +
                                       (q << 7) + (cq << 3));
      short8 hv;
#pragma unroll
      for (int x = 0; x < 8; ++x) {
        const float sv = a[x] + bv[x];
        const float u = __expf(2.0f * sv);
        const float tv = 1.0f - 2.0f * __builtin_amdgcn_rcpf(u + 1.0f);
        const __hip_bfloat16 hb = __float2bfloat16(tv);
        hv[x] = *(const short*)&hb;
      }
      *(short8*)(sH + ((size_t)((cq << 6) + r) << 3)) = hv;
    }
  };

  stage(0, 0);
  fillH(0);
  __syncthreads();   // drains stage(0) DMA + sH ds_writes

  f32x16 acc[2][4] = {};

  for (int ks = 0; ks < 32; ++ks) {
    const int b = ks & 1;
    if (ks < 31) {
      stage(ks + 1, b ^ 1);
      asm volatile("s_waitcnt vmcnt(4)" ::: "memory");  // stage(ks) landed
    } else {
      asm volatile("s_waitcnt vmcnt(0)" ::: "memory");
    }
    __builtin_amdgcn_sched_barrier(0);
    __builtin_amdgcn_s_barrier();
    __builtin_amdgcn_sched_barrier(0);

    // A fragments: chunk cq = 2*(ks&7)+q2, rows mi*32+l31 (conflict-free).
    const int cq = ((ks & 7) << 1) + q2;
    short8 af[2];
#pragma unroll
    for (int mi = 0; mi < 2; ++mi)
      af[mi] = *(const short8*)(sH + (((cq << 6) + (mi << 5) + l31) << 3));
    // B fragments: sB[b][q2][wn+ni*32+l31][0..8] (conflict-free).
    short8 bf[4];
#pragma unroll
    for (int ni = 0; ni < 4; ++ni)
      bf[ni] = *(const short8*)(&sB[b][0] +
                                (((q2 << 10) + wn + (ni << 5) + l31) << 3));
#pragma unroll
    for (int mi = 0; mi < 2; ++mi)
#pragma unroll
      for (int ni = 0; ni < 4; ++ni)
        acc[mi][ni] = __builtin_amdgcn_mfma_f32_32x32x16_bf16(
            af[mi], bf[ni], acc[mi][ni], 0, 0, 0);

    __builtin_amdgcn_sched_barrier(0);
    __builtin_amdgcn_s_barrier();   // sB[b] readers done before next DMA
    __builtin_amdgcn_sched_barrier(0);

    if ((ks & 7) == 7 && ks < 31) {
      fillH((ks + 1) >> 3);         // quarter boundary: refill sH
      __syncthreads();              // sH writes visible (drains vmcnt too; ok)
    }
  }

  // Epilogue: C/D layout (harness-verified R4/R5/R7/R8):
  // col = l&31, row = (rr&3) + 8*(rr>>2) + 4*q2.
#pragma unroll
  for (int ni = 0; ni < 4; ++ni) {
    const int col = wn + (ni << 5) + l31;
    const float bc = __bfloat162float(bias[col]);
#pragma unroll
    for (int mi = 0; mi < 2; ++mi) {
#pragma unroll
      for (int rr = 0; rr < 16; ++rr) {
        const int row = m0 + (mi << 5) + (rr & 3) + ((rr >> 2) << 3) + (q2 << 2);
        out[(size_t)row * 1024 + col] = acc[mi][ni][rr] + bc;
      }
    }
  }
}

// ---------------------------------------------------------------------------
extern "C" void kernel_launch(void* const* d_in, const int* in_sizes, int n_in,
                              void* d_out, int out_size, void* d_ws,
                              size_t ws_size, hipStream_t stream) {
  // ws: 0 flags | 256 bf16 copies (3.41MB) | 4MB Pe (2MB) | 6MB Pd (0.5MB)
  //     | 8MB WT (1MB, chunk-transposed W_out)
  char* ws = (char*)d_ws;
  int* flags = (int*)ws;
  __hip_bfloat16* cp = (__hip_bfloat16*)(ws + 256);
  float* Pe = (float*)(ws + (4ull << 20));
  float* Pd = (float*)(ws + (6ull << 20));
  __hip_bfloat16* WT = (__hip_bfloat16*)(ws + (8ull << 20));

  detect_kernel<<<dim3(1), dim3(512), 0, stream>>>(
      d_in[0], d_in[1], d_in[2], d_in[3], d_in[4], d_in[5], d_in[6], flags);
  convert_kernel<<<dim3((CTOT + 255) / 256), dim3(256), 0, stream>>>(
      d_in[0], d_in[1], d_in[2], d_in[3], d_in[4], d_in[5], d_in[6], flags, cp);

  const __hip_bfloat16* enc_c = cp + CU0;
  const __hip_bfloat16* dec_c = cp + CU1;
  const __hip_bfloat16* Wenc_c = cp + CU2;
  const __hip_bfloat16* benc_c = cp + CU3;
  const __hip_bfloat16* Wdec_c = cp + CU4;
  const __hip_bfloat16* Wout_c = cp + CU5;
  const __hip_bfloat16* bout_c = cp + CU6;

  proj_kernel<<<dim3(48), dim3(256), 0, stream>>>(
      enc_c, Wenc_c, benc_c, dec_c, Wdec_c, Wout_c, WT, Pe, Pd);
  gemm_joint<<<dim3(1024), dim3(512), 0, stream>>>(
      Pe, Pd, WT, bout_c, (float*)d_out);
}

// Round 10
// 392.872 us; speedup vs baseline: 1.3168x; 1.0778x over previous
//
#include <hip/hip_runtime.h>
#include <hip/hip_bf16.h>

// RNN-T joint network. B=4 T=256 U=64 D=512 J=512 V=1024.
//   Pe = enc @ W_enc^T + b_enc   (1024 x 512)  fp32 in ws
//   Pd = dec @ W_dec^T           (256  x 512)  fp32 in ws
//   out[m,:] = tanh(Pe[m>>6] + Pd[(m>>14)*64 + (m&63)]) @ W_out^T + b_out
//
// gemm_joint (round-10): genuine 2 WG/CU on BOTH budgets + 2x barrier
// amortization. R9 lesson: acc[2][4]=128 VGPR + launch_bounds(512,2) ->
// ~190 VGPR/wave -> 1 WG/CU; every barrier uncovered (~2700cy/iter stall,
// all structures converge to ~170us). This round:
//   - acc[2][2] f32x16 = 64 VGPR, launch_bounds(512,4) cap 128 -> 2 WG.
//   - LDS 64KB: sH quarter-K [16cq][128r][8] 32KB (tanh once per block,
//     refilled 4x) + sB dbuf 2x16KB [4kq][256n][8]. Both lane-consecutive
//     16B on write AND read -> zero bank conflicts, no swizzle.
//   - BM=128, BN=256 (nb=4, tanh x4 ~= 14us device-wide VALU), BK=32 ->
//     16 tile-iters, 2 sub-steps each: per CU-tile MFMA 1033cy vs LDS
//     ~1250cy, barrier waits covered by sibling WG.
//   - WT pre-transpose kept (R9): stage = 2 contiguous gload_lds/thread,
//     counted vmcnt(2), dest = uniform + lane*16 (rule m104).

typedef __attribute__((ext_vector_type(8))) short short8;     // 8 bf16
typedef __attribute__((ext_vector_type(4))) float f32x4;
typedef __attribute__((ext_vector_type(8))) float f32x8;
typedef __attribute__((ext_vector_type(16))) float f32x16;

#define SZ0 524288
#define SZ1 131072
#define SZ2 262144
#define SZ3 512
#define SZ4 262144
#define SZ5 524288
#define SZ6 1024
#define CU0 0
#define CU1 524288
#define CU2 655360
#define CU3 917504
#define CU4 918016
#define CU5 1180160
#define CU6 1704448
#define CTOT 1705472

// ---------------------------------------------------------------------------
// Runtime dtype detection (unchanged).
// ---------------------------------------------------------------------------
__global__ void detect_kernel(const void* p0, const void* p1, const void* p2,
                              const void* p3, const void* p4, const void* p5,
                              const void* p6, int* flags) {
  const void* ps[7] = {p0, p1, p2, p3, p4, p5, p6};
  const int sz[7] = {SZ0, SZ1, SZ2, SZ3, SZ4, SZ5, SZ6};
  const int w = threadIdx.x >> 6;
  const int l = threadIdx.x & 63;
  if (w >= 7) return;
  const unsigned short* u = (const unsigned short*)ps[w];
  const int lim = sz[w] < 1024 ? sz[w] : 1024;
  int bad = 0;
  for (int j = l; j < lim; j += 64) {
    const unsigned e = (u[j] >> 7) & 0xFFu;
    if (e >= 0x8Eu) bad = 1;
  }
  const unsigned long long b = __ballot(bad);
  if (l == 0) flags[w] = (b != 0ULL) ? 1 : 0;
}

__global__ __launch_bounds__(256) void convert_kernel(
    const void* p0, const void* p1, const void* p2, const void* p3,
    const void* p4, const void* p5, const void* p6,
    const int* __restrict__ flags, __hip_bfloat16* __restrict__ dst) {
  const int gid = blockIdx.x * 256 + threadIdx.x;
  if (gid >= CTOT) return;
  int t, local;
  const void* p;
  if (gid < CU1)      { t = 0; local = gid - CU0; p = p0; }
  else if (gid < CU2) { t = 1; local = gid - CU1; p = p1; }
  else if (gid < CU3) { t = 2; local = gid - CU2; p = p2; }
  else if (gid < CU4) { t = 3; local = gid - CU3; p = p3; }
  else if (gid < CU5) { t = 4; local = gid - CU4; p = p4; }
  else if (gid < CU6) { t = 5; local = gid - CU5; p = p5; }
  else                { t = 6; local = gid - CU6; p = p6; }
  __hip_bfloat16 v;
  if (flags[t])
    v = __float2bfloat16(((const float*)p)[local]);
  else
    v = ((const __hip_bfloat16*)p)[local];
  dst[gid] = v;
}

// ---------------------------------------------------------------------------
// m97-structure GEMM body for the two small projections (unchanged).
// ---------------------------------------------------------------------------
__device__ __forceinline__ void gemm_bt_body(
    const __hip_bfloat16* __restrict__ A, const __hip_bfloat16* __restrict__ Bw,
    const __hip_bfloat16* __restrict__ bias, float* __restrict__ C,
    int M, int N, int K, int bid,
    __hip_bfloat16* sA, __hip_bfloat16* sB) {
  const int tid = threadIdx.x;
  const int w = tid >> 6;
  const int l = tid & 63;
  const int ntiles = N >> 7;
  const int mt = bid / ntiles;
  const int nt = bid % ntiles;
  const int m0 = mt << 7;
  const int n0 = nt << 7;
  const int wm = (w >> 1) << 6;
  const int wn = (w & 1) << 6;
  const int r16 = l & 15;
  const int q = l >> 4;

  f32x4 acc[4][4] = {};

  const int srow_in = l >> 3;
  const int scol = (l & 7) << 3;

  for (int k0 = 0; k0 < K; k0 += 64) {
#pragma unroll
    for (int i = 0; i < 4; ++i) {
      const int c = (w << 2) + i;
      const int row = (c << 3) + srow_in;
      const __hip_bfloat16* gA = A + (size_t)(m0 + row) * K + k0 + scol;
      const __hip_bfloat16* gB = Bw + (size_t)(n0 + row) * K + k0 + scol;
      __builtin_amdgcn_global_load_lds(
          (const __attribute__((address_space(1))) void*)gA,
          (__attribute__((address_space(3))) void*)(sA + (c << 9) + (l << 3)),
          16, 0, 0);
      __builtin_amdgcn_global_load_lds(
          (const __attribute__((address_space(1))) void*)gB,
          (__attribute__((address_space(3))) void*)(sB + (c << 9) + (l << 3)),
          16, 0, 0);
    }
    __syncthreads();

#pragma unroll
    for (int kk = 0; kk < 2; ++kk) {
      const int kc = (kk << 5) + (q << 3);
      short8 af[4], bf[4];
#pragma unroll
      for (int mi = 0; mi < 4; ++mi)
        af[mi] = *(const short8*)(sA + (wm + (mi << 4) + r16) * 64 + kc);
#pragma unroll
      for (int ni = 0; ni < 4; ++ni)
        bf[ni] = *(const short8*)(sB + (wn + (ni << 4) + r16) * 64 + kc);
#pragma unroll
      for (int mi = 0; mi < 4; ++mi)
#pragma unroll
        for (int ni = 0; ni < 4; ++ni)
          acc[mi][ni] = __builtin_amdgcn_mfma_f32_16x16x32_bf16(
              af[mi], bf[ni], acc[mi][ni], 0, 0, 0);
    }
    __syncthreads();
  }

#pragma unroll
  for (int ni = 0; ni < 4; ++ni) {
    const int col = n0 + wn + (ni << 4) + r16;
    const float bc = bias ? __bfloat162float(bias[col]) : 0.0f;
#pragma unroll
    for (int mi = 0; mi < 4; ++mi) {
      const int rowb = m0 + wm + (mi << 4) + (q << 2);
#pragma unroll
      for (int i = 0; i < 4; ++i)
        C[(size_t)(rowb + i) * N + col] = acc[mi][ni][i] + bc;
    }
  }
}

// proj blocks 0..39: Pe/Pd GEMMs. Blocks 40..47: W_out -> WT transpose,
// WT[(k>>3)*1024 + n][8] = W_out[n][k&~7 .. +8]  (chunk-major, 1MB).
__global__ __launch_bounds__(256) void proj_kernel(
    const __hip_bfloat16* __restrict__ enc, const __hip_bfloat16* __restrict__ Wenc,
    const __hip_bfloat16* __restrict__ benc,
    const __hip_bfloat16* __restrict__ dec, const __hip_bfloat16* __restrict__ Wdec,
    const __hip_bfloat16* __restrict__ Wout, __hip_bfloat16* __restrict__ WT,
    float* __restrict__ Pe, float* __restrict__ Pd) {
  __shared__ __align__(16) __hip_bfloat16 sA[128 * 64];
  __shared__ __align__(16) __hip_bfloat16 sB[128 * 64];
  if (blockIdx.x < 32) {
    gemm_bt_body(enc, Wenc, benc, Pe, 1024, 512, 512, blockIdx.x, sA, sB);
  } else if (blockIdx.x < 40) {
    gemm_bt_body(dec, Wdec, nullptr, Pd, 256, 512, 512, blockIdx.x - 32, sA, sB);
  } else {
    const int bid = blockIdx.x - 40;            // 0..7
#pragma unroll
    for (int i = 0; i < 32; ++i) {
      const int cid = (bid << 13) + (i << 8) + threadIdx.x;  // 0..65535
      const int n = cid >> 6;
      const int c = cid & 63;
      *(short8*)(WT + (((size_t)c << 10) + n) * 8) =
          *(const short8*)(Wout + (size_t)n * 512 + (c << 3));
    }
  }
}

// ---------------------------------------------------------------------------
// Main fused GEMM. grid = 2048 blocks (512 mb x 4 nb), 512 threads (8 waves),
// 2 WG/CU (64KB LDS, <=128 VGPR via launch_bounds(512,4)).
// Wave grid 2(M)x4(N): wm=(w>>2)*64, wn=(w&3)*64; wave-tile 64x64,
// acc[2][2] f32x16 = 64 VGPR. 16 tile-iters (BK=32), 2 sub-steps each.
// Per tile/wave: 2 gload_lds (stage next from WT, contiguous), 8 ds_read,
// 8 MFMA, counted vmcnt(2), 2 raw barriers. sH refilled at kt=4,8,12.
// ---------------------------------------------------------------------------
__global__ __launch_bounds__(512, 4) void gemm_joint(
    const float* __restrict__ Pe, const float* __restrict__ Pd,
    const __hip_bfloat16* __restrict__ WT,
    const __hip_bfloat16* __restrict__ bias, float* __restrict__ out) {
  __shared__ __align__(16) __hip_bfloat16 sH[16 * 128 * 8];     // 32 KB
  __shared__ __align__(16) __hip_bfloat16 sB[2][4 * 256 * 8];   // 2 x 16 KB

  const int t = threadIdx.x;
  const int w = t >> 6;
  const int l = t & 63;
  const int l31 = l & 31;
  const int q2 = l >> 5;
  const int mb = blockIdx.x >> 2;
  const int nb = blockIdx.x & 3;
  const int m0 = mb << 7;
  const int n0 = nb << 8;

  // STAGE: sB[b] <- WT k-chunks [kt*4 .. kt*4+4) x cols [n0, n0+256).
  // slot = h*512 + t: kq = slot>>8, n = slot&255. Source contiguous 16B
  // per lane within each kq-run; dest = uniform + lane*16 (rule m104).
  auto stage = [&](int kt, int b) {
#pragma unroll
    for (int h = 0; h < 2; ++h) {
      const int slot = (h << 9) + t;
      const int kq = slot >> 8;
      const int n = slot & 255;
      const __hip_bfloat16* src =
          WT + (((size_t)((kt << 2) + kq) << 10) + n0 + n) * 8;
      __builtin_amdgcn_global_load_lds(
          (const __attribute__((address_space(1))) void*)src,
          (__attribute__((address_space(3))) void*)(&sB[b][0] + (slot << 3)),
          16, 0, 0);
    }
  };

  // FILL: sH[cq][r][8] = tanh(Pe[e][q*128+cq*8+..] + Pd[d][...]),
  // quarter q. slot s = s2*512 + t: r = t&127, cq = s2*4 + (t>>7).
  // Pe load is wave-uniform (broadcast); Pd is a 64-row gather (L2-hot).
  auto fillH = [&](int q) {
    const int r = t & 127;
    const int e = (mb << 1) + (r >> 6);
    const int d = ((mb >> 7) << 6) | (r & 63);
    const float* peR = Pe + (size_t)e * 512 + (q << 7);
    const float* pdR = Pd + (size_t)d * 512 + (q << 7);
#pragma unroll
    for (int s2 = 0; s2 < 4; ++s2) {
      const int cq = (s2 << 2) + (t >> 7);   // 0..15
      const f32x8 a = *(const f32x8*)(peR + (cq << 3));
      const f32x8 bv = *(const f32x8*)(pdR + (cq << 3));
      short8 hv;
#pragma unroll
      for (int x = 0; x < 8; ++x) {
        const float sv = a[x] + bv[x];
        const float u = __expf(2.0f * sv);
        const float tv = 1.0f - 2.0f * __builtin_amdgcn_rcpf(u + 1.0f);
        const __hip_bfloat16 hb = __float2bfloat16(tv);
        hv[x] = *(const short*)&hb;
      }
      *(short8*)(sH + ((size_t)((cq << 7) + r) << 3)) = hv;
    }
  };

  stage(0, 0);
  fillH(0);
  __syncthreads();   // full drain once: stage(0) DMA + sH writes

  const int wm = (w >> 2) << 6;   // 0 or 64 (M)
  const int wn = (w & 3) << 6;    // 0,64,128,192 (N)
  f32x16 acc[2][2] = {};

  for (int kt = 0; kt < 16; ++kt) {
    const int b = kt & 1;
    if (kt < 15) {
      stage(kt + 1, b ^ 1);
      asm volatile("s_waitcnt vmcnt(2)" ::: "memory");  // stage(kt) landed
    } else {
      asm volatile("s_waitcnt vmcnt(0)" ::: "memory");
    }
    __builtin_amdgcn_sched_barrier(0);
    __builtin_amdgcn_s_barrier();        // barrier A: sB[b] ready for all
    __builtin_amdgcn_sched_barrier(0);

    if ((kt & 3) == 0 && kt) {
      // Quarter boundary: refill sH (prev quarter's readers finished at
      // the previous end-barrier). lgkmcnt(0) before barrier: ds_writes
      // complete before any wave reads.
      fillH(kt >> 2);
      asm volatile("s_waitcnt lgkmcnt(0)" ::: "memory");
      __builtin_amdgcn_sched_barrier(0);
      __builtin_amdgcn_s_barrier();
      __builtin_amdgcn_sched_barrier(0);
    }

#pragma unroll
    for (int ss = 0; ss < 2; ++ss) {
      const int kq = (ss << 1) + q2;                  // sB k-chunk
      const int cq = ((kt & 3) << 2) + kq;            // sH k-chunk in quarter
      short8 af[2], bf[2];
#pragma unroll
      for (int mi = 0; mi < 2; ++mi)
        af[mi] = *(const short8*)(sH +
                                  (((cq << 7) + wm + (mi << 5) + l31) << 3));
#pragma unroll
      for (int ni = 0; ni < 2; ++ni)
        bf[ni] = *(const short8*)(&sB[b][0] +
                                  (((kq << 8) + wn + (ni << 5) + l31) << 3));
#pragma unroll
      for (int mi = 0; mi < 2; ++mi)
#pragma unroll
        for (int ni = 0; ni < 2; ++ni)
          acc[mi][ni] = __builtin_amdgcn_mfma_f32_32x32x16_bf16(
              af[mi], bf[ni], acc[mi][ni], 0, 0, 0);
    }

    __builtin_amdgcn_sched_barrier(0);
    __builtin_amdgcn_s_barrier();        // barrier C: sB[b] readers done
    __builtin_amdgcn_sched_barrier(0);
  }

  // Epilogue: C/D layout (harness-verified R4/R5/R7/R8/R9):
  // col = l&31, row = (rr&3) + 8*(rr>>2) + 4*q2.
#pragma unroll
  for (int ni = 0; ni < 2; ++ni) {
    const int col = n0 + wn + (ni << 5) + l31;
    const float bc = __bfloat162float(bias[col]);
#pragma unroll
    for (int mi = 0; mi < 2; ++mi) {
#pragma unroll
      for (int rr = 0; rr < 16; ++rr) {
        const int row = m0 + wm + (mi << 5) + (rr & 3) + ((rr >> 2) << 3) +
                        (q2 << 2);
        out[(size_t)row * 1024 + col] = acc[mi][ni][rr] + bc;
      }
    }
  }
}

// ---------------------------------------------------------------------------
extern "C" void kernel_launch(void* const* d_in, const int* in_sizes, int n_in,
                              void* d_out, int out_size, void* d_ws,
                              size_t ws_size, hipStream_t stream) {
  // ws: 0 flags | 256 bf16 copies (3.41MB) | 4MB Pe (2MB) | 6MB Pd (0.5MB)
  //     | 8MB WT (1MB, chunk-transposed W_out)
  char* ws = (char*)d_ws;
  int* flags = (int*)ws;
  __hip_bfloat16* cp = (__hip_bfloat16*)(ws + 256);
  float* Pe = (float*)(ws + (4ull << 20));
  float* Pd = (float*)(ws + (6ull << 20));
  __hip_bfloat16* WT = (__hip_bfloat16*)(ws + (8ull << 20));

  detect_kernel<<<dim3(1), dim3(512), 0, stream>>>(
      d_in[0], d_in[1], d_in[2], d_in[3], d_in[4], d_in[5], d_in[6], flags);
  convert_kernel<<<dim3((CTOT + 255) / 256), dim3(256), 0, stream>>>(
      d_in[0], d_in[1], d_in[2], d_in[3], d_in[4], d_in[5], d_in[6], flags, cp);

  const __hip_bfloat16* enc_c = cp + CU0;
  const __hip_bfloat16* dec_c = cp + CU1;
  const __hip_bfloat16* Wenc_c = cp + CU2;
  const __hip_bfloat16* benc_c = cp + CU3;
  const __hip_bfloat16* Wdec_c = cp + CU4;
  const __hip_bfloat16* Wout_c = cp + CU5;
  const __hip_bfloat16* bout_c = cp + CU6;

  proj_kernel<<<dim3(48), dim3(256), 0, stream>>>(
      enc_c, Wenc_c, benc_c, dec_c, Wdec_c, Wout_c, WT, Pe, Pd);
  gemm_joint<<<dim3(2048), dim3(512), 0, stream>>>(
      Pe, Pd, WT, bout_c, (float*)d_out);
}